// Round 3
// baseline (1182.538 us; speedup 1.0000x reference)
//
#include <hip/hip_runtime.h>
#include <stdint.h>

typedef unsigned int uint;
typedef unsigned short ushort;
typedef __attribute__((ext_vector_type(4))) float f32x4;
typedef __attribute__((ext_vector_type(8))) short bf16x8;   // 8 bf16 in 4 VGPRs

union U4H8 { uint4 u; bf16x8 h; };

__device__ __forceinline__ float bflo(uint u){ return __uint_as_float(u << 16); }
__device__ __forceinline__ float bfhi(uint u){ return __uint_as_float(u & 0xffff0000u); }
__device__ __forceinline__ ushort f2bf(float f){
  uint u = __float_as_uint(f);
  return (ushort)((u + 0x7fffu + ((u >> 16) & 1u)) >> 16);   // RNE
}
__device__ __forceinline__ uint pack2(float lo, float hi){
  return ((uint)f2bf(hi) << 16) | (uint)f2bf(lo);
}

// ---------------------------------------------------------------------------
// xn[v] = x[v] / ||x[v]||  -> bf16 packed row-major [N][128] (uint[N][64])
// ---------------------------------------------------------------------------
__global__ __launch_bounds__(256) void k_norm(const float* __restrict__ x,
    uint* __restrict__ xn_u, int n)
{
  int w = threadIdx.x >> 6, l = threadIdx.x & 63;
  for (int v = blockIdx.x*4 + w; v < n; v += gridDim.x*4) {
    float2 xv = ((const float2*)x)[(size_t)v*64 + l];
    float ss = xv.x*xv.x + xv.y*xv.y;
    #pragma unroll
    for (int off = 32; off > 0; off >>= 1) ss += __shfl_down(ss, off, 64);
    ss = __shfl(ss, 0, 64);
    float inv = (ss > 0.f) ? rsqrtf(ss) : 1.f;
    xn_u[(size_t)v*64 + l] = pack2(xv.x*inv, xv.y*inv);
  }
}

// ---------------------------------------------------------------------------
// MFMA GEMM #1: mu[v][p] = relu( (xn @ th2^T)[v][p] + th1[p][0]*sv + th1[p][1]*tv )
// 16x16x32 frags; D mapping: col=lane&15, row=(lane>>4)*4+reg  [m89/m91].
// ---------------------------------------------------------------------------
__global__ __launch_bounds__(256) void k_mu(
    const uint4* __restrict__ xn4, const float* __restrict__ sv,
    const float* __restrict__ tv, const float* __restrict__ th1,
    const float* __restrict__ th2, ushort* __restrict__ mu_s, int n)
{
  __shared__ uint4 B[2048];   // [s:4][t:8][lane:64], 32 KB
  const int tid = threadIdx.x;
  for (int f = tid; f < 2048; f += 256) {
    int l = f & 63, rest = f >> 6;          // rest: 0..31
    int s = rest >> 3, t = rest & 7;
    int row = t*16 + (l & 15);              // W row (output col p)
    int kb  = s*32 + (l >> 4)*8;
    const float* p = th2 + row*128 + kb;
    float4 a = *(const float4*)p;
    float4 b = *(const float4*)(p + 4);
    uint4 u; u.x = pack2(a.x,a.y); u.y = pack2(a.z,a.w);
    u.z = pack2(b.x,b.y); u.w = pack2(b.z,b.w);
    B[(s*8 + t)*64 + l] = u;
  }
  __syncthreads();
  const int w = tid >> 6, l = tid & 63, q = l >> 4, c = l & 15;
  float2 t1[8];
  #pragma unroll
  for (int t = 0; t < 8; ++t) t1[t] = ((const float2*)th1)[t*16 + c];
  const int ntiles = (n + 15) >> 4;
  for (int T = blockIdx.x*4 + w; T < ntiles; T += gridDim.x*4) {
    int v0 = T*16;
    int arow = min(v0 + c, n-1);
    U4H8 a[4];
    #pragma unroll
    for (int s = 0; s < 4; ++s) a[s].u = xn4[(size_t)arow*16 + s*4 + q];
    f32x4 acc[8];
    #pragma unroll
    for (int t = 0; t < 8; ++t) acc[t] = (f32x4){0.f,0.f,0.f,0.f};
    #pragma unroll
    for (int s = 0; s < 4; ++s) {
      #pragma unroll
      for (int t = 0; t < 8; ++t) {
        U4H8 b; b.u = B[(s*8 + t)*64 + l];
        acc[t] = __builtin_amdgcn_mfma_f32_16x16x32_bf16(a[s].h, b.h, acc[t], 0, 0, 0);
      }
    }
    float svr[4], tvr[4];
    #pragma unroll
    for (int r = 0; r < 4; ++r) {
      int node = min(v0 + q*4 + r, n-1);
      svr[r] = sv[node]; tvr[r] = tv[node];
    }
    #pragma unroll
    for (int t = 0; t < 8; ++t) {
      #pragma unroll
      for (int r = 0; r < 4; ++r) {
        int node = v0 + q*4 + r;
        if (node < n) {
          float m = fmaxf(acc[t][r] + t1[t].x*svr[r] + t1[t].y*tvr[r], 0.f);
          mu_s[(size_t)node*128 + t*16 + c] = f2bf(m);
        }
      }
    }
  }
}

// --------------------- bucketed CSR build (write-local) ---------------------
// Bucket = src>>7 (128 nodes). Fixed-capacity padded regions: no global scan.
// packed entry = (src&127)<<17 | dst   (valid while n < 2^17)

__global__ void k_binit(int* __restrict__ bcur, int nbuck, int cap) {
  int i = blockIdx.x*256 + threadIdx.x;
  if (i < nbuck) bcur[i] = i * cap;
}

__global__ void k_bucketA(const int* __restrict__ src, const int* __restrict__ dst,
                          int* __restrict__ bcur, uint* __restrict__ packed,
                          int e, int cap) {
  int i = blockIdx.x*256 + threadIdx.x;
  if (i < e) {
    int s = src[i], d = dst[i];
    int b = s >> 7;
    int pos = atomicAdd(&bcur[b], 1);
    if (pos < (b + 1) * cap)               // 8-sigma headroom; never expected
      packed[pos] = ((uint)(s & 127) << 17) | (uint)d;
  }
}

// One block per bucket: LDS histogram -> scan -> rowstart/cnt, then scatter
// dst into a contiguous (L2-resident) 16 KB window of sorted.
__global__ __launch_bounds__(256) void k_bucketB(
    const uint* __restrict__ packed, const int* __restrict__ bcur,
    int* __restrict__ sorted, int* __restrict__ rowstart,
    int* __restrict__ cnt, int n, int cap)
{
  __shared__ int lc[128];
  __shared__ int lofs[128];
  __shared__ int lcur[128];
  const int b = blockIdx.x, tid = threadIdx.x;
  const int base = b * cap;
  const int size = min(bcur[b] - base, cap);
  if (tid < 128) lc[tid] = 0;
  __syncthreads();
  for (int i = tid; i < size; i += 256)
    atomicAdd(&lc[packed[base + i] >> 17], 1);
  __syncthreads();
  if (tid < 128) lofs[tid] = lc[tid];
  __syncthreads();
  for (int off = 1; off < 128; off <<= 1) {
    int t = 0;
    if (tid < 128 && tid >= off) t = lofs[tid - off];
    __syncthreads();
    if (tid < 128) lofs[tid] += t;
    __syncthreads();
  }
  if (tid < 128) {
    int node = (b << 7) + tid;
    int excl = lofs[tid] - lc[tid];
    lcur[tid] = base + excl;
    if (node < n) { rowstart[node] = base + excl; cnt[node] = lc[tid]; }
  }
  __syncthreads();
  for (int i = tid; i < size; i += 256) {
    uint p = packed[base + i];
    int q = atomicAdd(&lcur[p >> 17], 1);
    sorted[q] = (int)(p & 0x1FFFFu);
  }
}

// ---------------------------------------------------------------------------
// Gather: rs[v] = relu(deg*mu[v] - sum_{u in N(v)} mu[u])  bf16 [N][128]
// Zero LDS (full occupancy); 8 independent row-loads in flight per batch.
// ---------------------------------------------------------------------------
__global__ __launch_bounds__(256) void k_gather(
    const uint* __restrict__ mu_u, const int* __restrict__ sorted,
    const int* __restrict__ cnt, const int* __restrict__ rowstart,
    uint* __restrict__ rs_u, int n)
{
  int w = threadIdx.x >> 6, l = threadIdx.x & 63;
  for (int v = blockIdx.x*4 + w; v < n; v += gridDim.x*4) {
    int deg = cnt[v], start = rowstart[v];
    float nb0 = 0.f, nb1 = 0.f;
    for (int base = 0; base < deg; base += 64) {
      int m = min(deg - base, 64);
      int idx = (l < m) ? sorted[start + base + l] : 0;
      int j = 0;
      for (; j + 8 <= m; j += 8) {
        uint u0 = mu_u[(size_t)__shfl(idx, j+0, 64)*64 + l];
        uint u1 = mu_u[(size_t)__shfl(idx, j+1, 64)*64 + l];
        uint u2 = mu_u[(size_t)__shfl(idx, j+2, 64)*64 + l];
        uint u3 = mu_u[(size_t)__shfl(idx, j+3, 64)*64 + l];
        uint u4 = mu_u[(size_t)__shfl(idx, j+4, 64)*64 + l];
        uint u5 = mu_u[(size_t)__shfl(idx, j+5, 64)*64 + l];
        uint u6 = mu_u[(size_t)__shfl(idx, j+6, 64)*64 + l];
        uint u7 = mu_u[(size_t)__shfl(idx, j+7, 64)*64 + l];
        nb0 += (bflo(u0)+bflo(u1)) + (bflo(u2)+bflo(u3))
             + (bflo(u4)+bflo(u5)) + (bflo(u6)+bflo(u7));
        nb1 += (bfhi(u0)+bfhi(u1)) + (bfhi(u2)+bfhi(u3))
             + (bfhi(u4)+bfhi(u5)) + (bfhi(u6)+bfhi(u7));
      }
      for (; j < m; ++j) {
        uint u = mu_u[(size_t)__shfl(idx, j, 64)*64 + l];
        nb0 += bflo(u); nb1 += bfhi(u);
      }
    }
    uint um = mu_u[(size_t)v*64 + l];
    float dg = (float)deg;
    float s0 = fmaxf(dg*bflo(um) - nb0, 0.f);
    float s1 = fmaxf(dg*bfhi(um) - nb1, 0.f);
    rs_u[(size_t)v*64 + l] = pack2(s0, s1);
  }
}

// ---------------------------------------------------------------------------
// MFMA GEMM #2: mu'[v] = [mu ; relu(s)] @ h_theta^T   (K=256)
// ---------------------------------------------------------------------------
__global__ __launch_bounds__(256) void k_mlp(
    const uint4* __restrict__ mu4, const uint4* __restrict__ rs4,
    const float* __restrict__ hth, ushort* __restrict__ mup_s, int n)
{
  __shared__ uint4 B[4096];   // [s:8][t:8][lane:64], 64 KB
  const int tid = threadIdx.x;
  for (int f = tid; f < 4096; f += 256) {
    int l = f & 63, rest = f >> 6;          // 0..63
    int s = rest >> 3, t = rest & 7;
    int row = t*16 + (l & 15);
    int kb  = s*32 + (l >> 4)*8;
    const float* p = hth + row*256 + kb;
    float4 a = *(const float4*)p;
    float4 b = *(const float4*)(p + 4);
    uint4 u; u.x = pack2(a.x,a.y); u.y = pack2(a.z,a.w);
    u.z = pack2(b.x,b.y); u.w = pack2(b.z,b.w);
    B[(s*8 + t)*64 + l] = u;
  }
  __syncthreads();
  const int w = tid >> 6, l = tid & 63, q = l >> 4, c = l & 15;
  const int ntiles = (n + 15) >> 4;
  for (int T = blockIdx.x*4 + w; T < ntiles; T += gridDim.x*4) {
    int v0 = T*16;
    int arow = min(v0 + c, n-1);
    U4H8 a[8];
    #pragma unroll
    for (int s = 0; s < 4; ++s) a[s].u   = mu4[(size_t)arow*16 + s*4 + q];
    #pragma unroll
    for (int s = 0; s < 4; ++s) a[4+s].u = rs4[(size_t)arow*16 + s*4 + q];
    f32x4 acc[8];
    #pragma unroll
    for (int t = 0; t < 8; ++t) acc[t] = (f32x4){0.f,0.f,0.f,0.f};
    #pragma unroll
    for (int s = 0; s < 8; ++s) {
      #pragma unroll
      for (int t = 0; t < 8; ++t) {
        U4H8 b; b.u = B[(s*8 + t)*64 + l];
        acc[t] = __builtin_amdgcn_mfma_f32_16x16x32_bf16(a[s].h, b.h, acc[t], 0, 0, 0);
      }
    }
    #pragma unroll
    for (int t = 0; t < 8; ++t) {
      #pragma unroll
      for (int r = 0; r < 4; ++r) {
        int node = v0 + q*4 + r;
        if (node < n) mup_s[(size_t)node*128 + t*16 + c] = f2bf(acc[t][r]);
      }
    }
  }
}

// column sums of mu' -> gsum[128]
__global__ __launch_bounds__(256) void k_colsum(const uint* __restrict__ mup_u,
    float* __restrict__ gsum, int n) {
  int w = threadIdx.x >> 6, l = threadIdx.x & 63;
  float a0 = 0.f, a1 = 0.f;
  for (int v = blockIdx.x*4 + w; v < n; v += gridDim.x*4) {
    uint u = mup_u[(size_t)v*64 + l];
    a0 += bflo(u); a1 += bfhi(u);
  }
  atomicAdd(&gsum[2*l],   a0);
  atomicAdd(&gsum[2*l+1], a1);
}

// up = th4 @ gsum; C = sum_p th3[p]*relu(up[p])
__global__ __launch_bounds__(128) void k_upC(const float* __restrict__ gsum,
    const float* __restrict__ th4, const float* __restrict__ th3,
    float* __restrict__ Cbuf) {
  __shared__ float S[128];
  __shared__ float part[128];
  int tid = threadIdx.x;
  S[tid] = gsum[tid];
  __syncthreads();
  float up = 0.f;
  const float4* r4 = (const float4*)(th4 + tid*128);
  const float4* S4 = (const float4*)S;
  #pragma unroll 8
  for (int qq = 0; qq < 32; ++qq) {
    float4 wv = r4[qq], av = S4[qq];
    up += wv.x*av.x + wv.y*av.y + wv.z*av.z + wv.w*av.w;
  }
  float r = th3[tid] * fmaxf(up, 0.f);
  part[tid] = r; __syncthreads();
  if (tid < 64) part[tid] += part[tid + 64];
  __syncthreads();
  if (tid < 64) {
    float v = part[tid];
    #pragma unroll
    for (int off = 32; off > 0; off >>= 1) v += __shfl_down(v, off, 64);
    if (tid == 0) Cbuf[0] = v;
  }
}

// ---------------------------------------------------------------------------
// MFMA GEMM #3 + epilogue: out[v] = C + sum_p th3[128+p]*relu((mu' @ th5^T)[v][p])
// ---------------------------------------------------------------------------
__global__ __launch_bounds__(256) void k_final(
    const uint4* __restrict__ mup4, const float* __restrict__ th5,
    const float* __restrict__ th3, const float* __restrict__ Cbuf,
    float* __restrict__ out, int n)
{
  __shared__ uint4 B[2048];   // 32 KB
  const int tid = threadIdx.x;
  for (int f = tid; f < 2048; f += 256) {
    int l = f & 63, rest = f >> 6;
    int s = rest >> 3, t = rest & 7;
    int row = t*16 + (l & 15);
    int kb  = s*32 + (l >> 4)*8;
    const float* p = th5 + row*128 + kb;
    float4 a = *(const float4*)p;
    float4 b = *(const float4*)(p + 4);
    uint4 u; u.x = pack2(a.x,a.y); u.y = pack2(a.z,a.w);
    u.z = pack2(b.x,b.y); u.w = pack2(b.z,b.w);
    B[(s*8 + t)*64 + l] = u;
  }
  __syncthreads();
  const int w = tid >> 6, l = tid & 63, q = l >> 4, c = l & 15;
  float t3w[8];
  #pragma unroll
  for (int t = 0; t < 8; ++t) t3w[t] = th3[128 + t*16 + c];
  const float C = Cbuf[0];
  const int ntiles = (n + 15) >> 4;
  for (int T = blockIdx.x*4 + w; T < ntiles; T += gridDim.x*4) {
    int v0 = T*16;
    int arow = min(v0 + c, n-1);
    U4H8 a[4];
    #pragma unroll
    for (int s = 0; s < 4; ++s) a[s].u = mup4[(size_t)arow*16 + s*4 + q];
    f32x4 acc[8];
    #pragma unroll
    for (int t = 0; t < 8; ++t) acc[t] = (f32x4){0.f,0.f,0.f,0.f};
    #pragma unroll
    for (int s = 0; s < 4; ++s) {
      #pragma unroll
      for (int t = 0; t < 8; ++t) {
        U4H8 b; b.u = B[(s*8 + t)*64 + l];
        acc[t] = __builtin_amdgcn_mfma_f32_16x16x32_bf16(a[s].h, b.h, acc[t], 0, 0, 0);
      }
    }
    float red[4] = {0.f, 0.f, 0.f, 0.f};
    #pragma unroll
    for (int t = 0; t < 8; ++t) {
      #pragma unroll
      for (int r = 0; r < 4; ++r)
        red[r] += t3w[t] * fmaxf(acc[t][r], 0.f);
    }
    #pragma unroll
    for (int r = 0; r < 4; ++r) {
      #pragma unroll
      for (int off = 1; off < 16; off <<= 1)
        red[r] += __shfl_xor(red[r], off, 64);
    }
    if (c == 0) {
      #pragma unroll
      for (int r = 0; r < 4; ++r) {
        int node = v0 + q*4 + r;
        if (node < n) out[node] = C + red[r];
      }
    }
  }
}

extern "C" void kernel_launch(void* const* d_in, const int* in_sizes, int n_in,
                              void* d_out, int out_size, void* d_ws, size_t ws_size,
                              hipStream_t stream)
{
  const float* sv  = (const float*)d_in[0];
  const float* tv  = (const float*)d_in[1];
  const float* x   = (const float*)d_in[2];
  const int*   esrc= (const int*)d_in[3];
  const int*   edst= (const int*)d_in[4];
  const float* th1 = (const float*)d_in[5];
  const float* th2 = (const float*)d_in[6];
  const float* th3 = (const float*)d_in[7];
  const float* th4 = (const float*)d_in[8];
  const float* th5 = (const float*)d_in[9];
  const float* hth = (const float*)d_in[10];
  float* out = (float*)d_out;
  const int n = in_sizes[0];
  const int e = in_sizes[3];

  const int nbuck = (n + 127) >> 7;                    // 782 for n=100k
  const int cap   = (((e + nbuck - 1) / nbuck) + 511 + 255) & ~255;  // mean+~512, 256-aligned

  char* wp = (char*)d_ws;
  auto carve = [&](size_t bytes) { char* p = wp; wp += (bytes + 255) & ~(size_t)255; return p; };
  // R1 (25.6 MB): xn [k_norm..k_mu] -> packed [bucketA..bucketB] -> mu' [k_mlp..k_final]
  char*   R1    = (char*) carve((size_t)n*128*2 > (size_t)nbuck*cap*4
                                ? (size_t)n*128*2 : (size_t)nbuck*cap*4);
  ushort* mu_s  = (ushort*)carve((size_t)n*128*2);     // mu bf16 row-major
  ushort* rs_s  = (ushort*)carve((size_t)n*128*2);     // relu(s) bf16 row-major
  int*    sorted= (int*)   carve((size_t)nbuck*cap*4); // padded CSR adjacency
  int*    cnt   = (int*)   carve((size_t)n*4);
  int*    rowst = (int*)   carve((size_t)n*4);
  int*    bcur  = (int*)   carve((size_t)nbuck*4);
  float*  gsum  = (float*) carve(128*4);
  float*  Cbuf  = (float*) carve(256);

  uint*   xn    = (uint*)R1;
  uint*   packed= (uint*)R1;
  ushort* mup_s = (ushort*)R1;

  hipMemsetAsync(gsum, 0, 128*4, stream);

  k_norm   <<<1024, 256, 0, stream>>>(x, xn, n);
  k_mu     <<<1024, 256, 0, stream>>>((const uint4*)xn, sv, tv, th1, th2, mu_s, n);
  k_binit  <<<(nbuck + 255)/256, 256, 0, stream>>>(bcur, nbuck, cap);
  k_bucketA<<<(e + 255)/256, 256, 0, stream>>>(esrc, edst, bcur, packed, e, cap);
  k_bucketB<<<nbuck, 256, 0, stream>>>(packed, bcur, sorted, rowst, cnt, n, cap);
  k_gather <<<2048, 256, 0, stream>>>((const uint*)mu_s, sorted, cnt, rowst,
                                      (uint*)rs_s, n);
  k_mlp    <<<1024, 256, 0, stream>>>((const uint4*)mu_s, (const uint4*)rs_s,
                                      hth, mup_s, n);
  k_colsum <<<256, 256, 0, stream>>>((const uint*)mup_s, gsum, n);
  k_upC    <<<1, 128, 0, stream>>>(gsum, th4, th3, Cbuf);
  k_final  <<<1024, 256, 0, stream>>>((const uint4*)mup_s, th5, th3, Cbuf, out, n);
}

// Round 4
// 697.643 us; speedup vs baseline: 1.6950x; 1.6950x over previous
//
#include <hip/hip_runtime.h>
#include <stdint.h>

typedef unsigned int uint;
typedef unsigned short ushort;
typedef __attribute__((ext_vector_type(4))) float f32x4;
typedef __attribute__((ext_vector_type(8))) short bf16x8;   // 8 bf16 in 4 VGPRs

union U4H8 { uint4 u; bf16x8 h; };

__device__ __forceinline__ float bflo(uint u){ return __uint_as_float(u << 16); }
__device__ __forceinline__ float bfhi(uint u){ return __uint_as_float(u & 0xffff0000u); }
__device__ __forceinline__ ushort f2bf(float f){
  uint u = __float_as_uint(f);
  return (ushort)((u + 0x7fffu + ((u >> 16) & 1u)) >> 16);   // RNE
}
__device__ __forceinline__ uint pack2(float lo, float hi){
  return ((uint)f2bf(hi) << 16) | (uint)f2bf(lo);
}

// ---------------------------------------------------------------------------
// xn[v] = x[v] / ||x[v]||  -> bf16 packed row-major [N][128] (uint[N][64])
// ---------------------------------------------------------------------------
__global__ __launch_bounds__(256) void k_norm(const float* __restrict__ x,
    uint* __restrict__ xn_u, int n)
{
  int w = threadIdx.x >> 6, l = threadIdx.x & 63;
  for (int v = blockIdx.x*4 + w; v < n; v += gridDim.x*4) {
    float2 xv = ((const float2*)x)[(size_t)v*64 + l];
    float ss = xv.x*xv.x + xv.y*xv.y;
    #pragma unroll
    for (int off = 32; off > 0; off >>= 1) ss += __shfl_down(ss, off, 64);
    ss = __shfl(ss, 0, 64);
    float inv = (ss > 0.f) ? rsqrtf(ss) : 1.f;
    xn_u[(size_t)v*64 + l] = pack2(xv.x*inv, xv.y*inv);
  }
}

// ---------------------------------------------------------------------------
// MFMA GEMM #1: mu[v][p] = relu( (xn @ th2^T)[v][p] + th1[p][0]*sv + th1[p][1]*tv )
// 16x16x32 frags; D mapping: col=lane&15, row=(lane>>4)*4+reg  [m89/m91].
// ---------------------------------------------------------------------------
__global__ __launch_bounds__(256) void k_mu(
    const uint4* __restrict__ xn4, const float* __restrict__ sv,
    const float* __restrict__ tv, const float* __restrict__ th1,
    const float* __restrict__ th2, ushort* __restrict__ mu_s, int n)
{
  __shared__ uint4 B[2048];   // [s:4][t:8][lane:64], 32 KB
  const int tid = threadIdx.x;
  for (int f = tid; f < 2048; f += 256) {
    int l = f & 63, rest = f >> 6;          // rest: 0..31
    int s = rest >> 3, t = rest & 7;
    int row = t*16 + (l & 15);              // W row (output col p)
    int kb  = s*32 + (l >> 4)*8;
    const float* p = th2 + row*128 + kb;
    float4 a = *(const float4*)p;
    float4 b = *(const float4*)(p + 4);
    uint4 u; u.x = pack2(a.x,a.y); u.y = pack2(a.z,a.w);
    u.z = pack2(b.x,b.y); u.w = pack2(b.z,b.w);
    B[(s*8 + t)*64 + l] = u;
  }
  __syncthreads();
  const int w = tid >> 6, l = tid & 63, q = l >> 4, c = l & 15;
  float2 t1[8];
  #pragma unroll
  for (int t = 0; t < 8; ++t) t1[t] = ((const float2*)th1)[t*16 + c];
  const int ntiles = (n + 15) >> 4;
  for (int T = blockIdx.x*4 + w; T < ntiles; T += gridDim.x*4) {
    int v0 = T*16;
    int arow = min(v0 + c, n-1);
    U4H8 a[4];
    #pragma unroll
    for (int s = 0; s < 4; ++s) a[s].u = xn4[(size_t)arow*16 + s*4 + q];
    f32x4 acc[8];
    #pragma unroll
    for (int t = 0; t < 8; ++t) acc[t] = (f32x4){0.f,0.f,0.f,0.f};
    #pragma unroll
    for (int s = 0; s < 4; ++s) {
      #pragma unroll
      for (int t = 0; t < 8; ++t) {
        U4H8 b; b.u = B[(s*8 + t)*64 + l];
        acc[t] = __builtin_amdgcn_mfma_f32_16x16x32_bf16(a[s].h, b.h, acc[t], 0, 0, 0);
      }
    }
    float svr[4], tvr[4];
    #pragma unroll
    for (int r = 0; r < 4; ++r) {
      int node = min(v0 + q*4 + r, n-1);
      svr[r] = sv[node]; tvr[r] = tv[node];
    }
    #pragma unroll
    for (int t = 0; t < 8; ++t) {
      #pragma unroll
      for (int r = 0; r < 4; ++r) {
        int node = v0 + q*4 + r;
        if (node < n) {
          float m = fmaxf(acc[t][r] + t1[t].x*svr[r] + t1[t].y*tvr[r], 0.f);
          mu_s[(size_t)node*128 + t*16 + c] = f2bf(m);
        }
      }
    }
  }
}

// ------------------------------- CSR build ---------------------------------
// 100k-cursor atomics (32 ops/address: no serialization — round-3 lesson:
// device atomics serialize ~183 ns/op PER ADDRESS; keep cardinality high).
__global__ void k_count(const int* __restrict__ src, int* __restrict__ cnt, int e) {
  int i = blockIdx.x*256 + threadIdx.x;
  if (i < e) atomicAdd(&cnt[src[i]], 1);
}

__global__ __launch_bounds__(256) void k_scan1(const int* __restrict__ cnt,
    int* __restrict__ excl, int* __restrict__ bsum, int n) {
  __shared__ int tmp[256];
  int tid = threadIdx.x;
  int i = blockIdx.x*256 + tid;
  int c = (i < n) ? cnt[i] : 0;
  tmp[tid] = c; __syncthreads();
  for (int off = 1; off < 256; off <<= 1) {
    int t = (tid >= off) ? tmp[tid - off] : 0;
    __syncthreads();
    tmp[tid] += t;
    __syncthreads();
  }
  if (i < n) excl[i] = tmp[tid] - c;
  if (tid == 255) bsum[blockIdx.x] = tmp[255];
}

__global__ __launch_bounds__(512) void k_scan2(const int* __restrict__ bsum,
    int* __restrict__ bbase, int nb) {
  __shared__ int tmp[512];
  int tid = threadIdx.x;
  int c = (tid < nb) ? bsum[tid] : 0;
  tmp[tid] = c; __syncthreads();
  for (int off = 1; off < 512; off <<= 1) {
    int t = (tid >= off) ? tmp[tid - off] : 0;
    __syncthreads();
    tmp[tid] += t;
    __syncthreads();
  }
  if (tid < nb) bbase[tid] = tmp[tid] - c;
}

__global__ void k_initcur(const int* __restrict__ excl, const int* __restrict__ bbase,
                          int* __restrict__ rowstart, int* __restrict__ cursor, int n) {
  int i = blockIdx.x*256 + threadIdx.x;
  if (i < n) { int r = excl[i] + bbase[i >> 8]; rowstart[i] = r; cursor[i] = r; }
}

// XCD-partitioned scatter: group g = blockIdx&7 handles src in [g*n8,(g+1)*n8).
// Group g's writes hit a contiguous ~1.6 MB slice of sorted -> stays in that
// XCD's L2, 64B lines absorb all 16 partial writes locally (round-2 scatter
// wrote 194 MB to HBM for a 12.8 MB payload via cross-XCD line ping-pong).
// Cost: each group scans the full edge list (8x reads, L3-resident).
__global__ __launch_bounds__(256) void k_scatter8(
    const int* __restrict__ src, const int* __restrict__ dst,
    int* __restrict__ cursor, int* __restrict__ sorted, int e, int n8)
{
  const int grp = blockIdx.x & 7;
  const int blk = blockIdx.x >> 3;
  const int nblk = gridDim.x >> 3;
  const int lo = grp * n8, hi = lo + n8;
  for (int i = blk*256 + threadIdx.x; i < e; i += nblk*256) {
    int s = src[i];
    if (s >= lo && s < hi) {
      int p = atomicAdd(&cursor[s], 1);
      sorted[p] = dst[i];
    }
  }
}

// ---------------------------------------------------------------------------
// Gather: rs[v] = relu(deg*mu[v] - sum_{u in N(v)} mu[u])  bf16 [N][128]
// Zero LDS (full occupancy); 8 independent row-loads in flight per batch.
// ---------------------------------------------------------------------------
__global__ __launch_bounds__(256) void k_gather(
    const uint* __restrict__ mu_u, const int* __restrict__ sorted,
    const int* __restrict__ cnt, const int* __restrict__ rowstart,
    uint* __restrict__ rs_u, int n)
{
  int w = threadIdx.x >> 6, l = threadIdx.x & 63;
  for (int v = blockIdx.x*4 + w; v < n; v += gridDim.x*4) {
    int deg = cnt[v], start = rowstart[v];
    float nb0 = 0.f, nb1 = 0.f;
    for (int base = 0; base < deg; base += 64) {
      int m = min(deg - base, 64);
      int idx = (l < m) ? sorted[start + base + l] : 0;
      int j = 0;
      for (; j + 8 <= m; j += 8) {
        uint u0 = mu_u[(size_t)__shfl(idx, j+0, 64)*64 + l];
        uint u1 = mu_u[(size_t)__shfl(idx, j+1, 64)*64 + l];
        uint u2 = mu_u[(size_t)__shfl(idx, j+2, 64)*64 + l];
        uint u3 = mu_u[(size_t)__shfl(idx, j+3, 64)*64 + l];
        uint u4 = mu_u[(size_t)__shfl(idx, j+4, 64)*64 + l];
        uint u5 = mu_u[(size_t)__shfl(idx, j+5, 64)*64 + l];
        uint u6 = mu_u[(size_t)__shfl(idx, j+6, 64)*64 + l];
        uint u7 = mu_u[(size_t)__shfl(idx, j+7, 64)*64 + l];
        nb0 += (bflo(u0)+bflo(u1)) + (bflo(u2)+bflo(u3))
             + (bflo(u4)+bflo(u5)) + (bflo(u6)+bflo(u7));
        nb1 += (bfhi(u0)+bfhi(u1)) + (bfhi(u2)+bfhi(u3))
             + (bfhi(u4)+bfhi(u5)) + (bfhi(u6)+bfhi(u7));
      }
      for (; j < m; ++j) {
        uint u = mu_u[(size_t)__shfl(idx, j, 64)*64 + l];
        nb0 += bflo(u); nb1 += bfhi(u);
      }
    }
    uint um = mu_u[(size_t)v*64 + l];
    float dg = (float)deg;
    float s0 = fmaxf(dg*bflo(um) - nb0, 0.f);
    float s1 = fmaxf(dg*bfhi(um) - nb1, 0.f);
    rs_u[(size_t)v*64 + l] = pack2(s0, s1);
  }
}

// ---------------------------------------------------------------------------
// MFMA GEMM #2: mu'[v] = [mu ; relu(s)] @ h_theta^T   (K=256)
// ---------------------------------------------------------------------------
__global__ __launch_bounds__(256) void k_mlp(
    const uint4* __restrict__ mu4, const uint4* __restrict__ rs4,
    const float* __restrict__ hth, ushort* __restrict__ mup_s, int n)
{
  __shared__ uint4 B[4096];   // [s:8][t:8][lane:64], 64 KB
  const int tid = threadIdx.x;
  for (int f = tid; f < 4096; f += 256) {
    int l = f & 63, rest = f >> 6;          // 0..63
    int s = rest >> 3, t = rest & 7;
    int row = t*16 + (l & 15);
    int kb  = s*32 + (l >> 4)*8;
    const float* p = hth + row*256 + kb;
    float4 a = *(const float4*)p;
    float4 b = *(const float4*)(p + 4);
    uint4 u; u.x = pack2(a.x,a.y); u.y = pack2(a.z,a.w);
    u.z = pack2(b.x,b.y); u.w = pack2(b.z,b.w);
    B[(s*8 + t)*64 + l] = u;
  }
  __syncthreads();
  const int w = tid >> 6, l = tid & 63, q = l >> 4, c = l & 15;
  const int ntiles = (n + 15) >> 4;
  for (int T = blockIdx.x*4 + w; T < ntiles; T += gridDim.x*4) {
    int v0 = T*16;
    int arow = min(v0 + c, n-1);
    U4H8 a[8];
    #pragma unroll
    for (int s = 0; s < 4; ++s) a[s].u   = mu4[(size_t)arow*16 + s*4 + q];
    #pragma unroll
    for (int s = 0; s < 4; ++s) a[4+s].u = rs4[(size_t)arow*16 + s*4 + q];
    f32x4 acc[8];
    #pragma unroll
    for (int t = 0; t < 8; ++t) acc[t] = (f32x4){0.f,0.f,0.f,0.f};
    #pragma unroll
    for (int s = 0; s < 8; ++s) {
      #pragma unroll
      for (int t = 0; t < 8; ++t) {
        U4H8 b; b.u = B[(s*8 + t)*64 + l];
        acc[t] = __builtin_amdgcn_mfma_f32_16x16x32_bf16(a[s].h, b.h, acc[t], 0, 0, 0);
      }
    }
    #pragma unroll
    for (int t = 0; t < 8; ++t) {
      #pragma unroll
      for (int r = 0; r < 4; ++r) {
        int node = v0 + q*4 + r;
        if (node < n) mup_s[(size_t)node*128 + t*16 + c] = f2bf(acc[t][r]);
      }
    }
  }
}

// column sums of mu' -> gsum[128]
__global__ __launch_bounds__(256) void k_colsum(const uint* __restrict__ mup_u,
    float* __restrict__ gsum, int n) {
  int w = threadIdx.x >> 6, l = threadIdx.x & 63;
  float a0 = 0.f, a1 = 0.f;
  for (int v = blockIdx.x*4 + w; v < n; v += gridDim.x*4) {
    uint u = mup_u[(size_t)v*64 + l];
    a0 += bflo(u); a1 += bfhi(u);
  }
  atomicAdd(&gsum[2*l],   a0);
  atomicAdd(&gsum[2*l+1], a1);
}

// up = th4 @ gsum; C = sum_p th3[p]*relu(up[p])
__global__ __launch_bounds__(128) void k_upC(const float* __restrict__ gsum,
    const float* __restrict__ th4, const float* __restrict__ th3,
    float* __restrict__ Cbuf) {
  __shared__ float S[128];
  __shared__ float part[128];
  int tid = threadIdx.x;
  S[tid] = gsum[tid];
  __syncthreads();
  float up = 0.f;
  const float4* r4 = (const float4*)(th4 + tid*128);
  const float4* S4 = (const float4*)S;
  #pragma unroll 8
  for (int qq = 0; qq < 32; ++qq) {
    float4 wv = r4[qq], av = S4[qq];
    up += wv.x*av.x + wv.y*av.y + wv.z*av.z + wv.w*av.w;
  }
  float r = th3[tid] * fmaxf(up, 0.f);
  part[tid] = r; __syncthreads();
  if (tid < 64) part[tid] += part[tid + 64];
  __syncthreads();
  if (tid < 64) {
    float v = part[tid];
    #pragma unroll
    for (int off = 32; off > 0; off >>= 1) v += __shfl_down(v, off, 64);
    if (tid == 0) Cbuf[0] = v;
  }
}

// ---------------------------------------------------------------------------
// MFMA GEMM #3 + epilogue: out[v] = C + sum_p th3[128+p]*relu((mu' @ th5^T)[v][p])
// ---------------------------------------------------------------------------
__global__ __launch_bounds__(256) void k_final(
    const uint4* __restrict__ mup4, const float* __restrict__ th5,
    const float* __restrict__ th3, const float* __restrict__ Cbuf,
    float* __restrict__ out, int n)
{
  __shared__ uint4 B[2048];   // 32 KB
  const int tid = threadIdx.x;
  for (int f = tid; f < 2048; f += 256) {
    int l = f & 63, rest = f >> 6;
    int s = rest >> 3, t = rest & 7;
    int row = t*16 + (l & 15);
    int kb  = s*32 + (l >> 4)*8;
    const float* p = th5 + row*128 + kb;
    float4 a = *(const float4*)p;
    float4 b = *(const float4*)(p + 4);
    uint4 u; u.x = pack2(a.x,a.y); u.y = pack2(a.z,a.w);
    u.z = pack2(b.x,b.y); u.w = pack2(b.z,b.w);
    B[(s*8 + t)*64 + l] = u;
  }
  __syncthreads();
  const int w = tid >> 6, l = tid & 63, q = l >> 4, c = l & 15;
  float t3w[8];
  #pragma unroll
  for (int t = 0; t < 8; ++t) t3w[t] = th3[128 + t*16 + c];
  const float C = Cbuf[0];
  const int ntiles = (n + 15) >> 4;
  for (int T = blockIdx.x*4 + w; T < ntiles; T += gridDim.x*4) {
    int v0 = T*16;
    int arow = min(v0 + c, n-1);
    U4H8 a[4];
    #pragma unroll
    for (int s = 0; s < 4; ++s) a[s].u = mup4[(size_t)arow*16 + s*4 + q];
    f32x4 acc[8];
    #pragma unroll
    for (int t = 0; t < 8; ++t) acc[t] = (f32x4){0.f,0.f,0.f,0.f};
    #pragma unroll
    for (int s = 0; s < 4; ++s) {
      #pragma unroll
      for (int t = 0; t < 8; ++t) {
        U4H8 b; b.u = B[(s*8 + t)*64 + l];
        acc[t] = __builtin_amdgcn_mfma_f32_16x16x32_bf16(a[s].h, b.h, acc[t], 0, 0, 0);
      }
    }
    float red[4] = {0.f, 0.f, 0.f, 0.f};
    #pragma unroll
    for (int t = 0; t < 8; ++t) {
      #pragma unroll
      for (int r = 0; r < 4; ++r)
        red[r] += t3w[t] * fmaxf(acc[t][r], 0.f);
    }
    #pragma unroll
    for (int r = 0; r < 4; ++r) {
      #pragma unroll
      for (int off = 1; off < 16; off <<= 1)
        red[r] += __shfl_xor(red[r], off, 64);
    }
    if (c == 0) {
      #pragma unroll
      for (int r = 0; r < 4; ++r) {
        int node = v0 + q*4 + r;
        if (node < n) out[node] = C + red[r];
      }
    }
  }
}

extern "C" void kernel_launch(void* const* d_in, const int* in_sizes, int n_in,
                              void* d_out, int out_size, void* d_ws, size_t ws_size,
                              hipStream_t stream)
{
  const float* sv  = (const float*)d_in[0];
  const float* tv  = (const float*)d_in[1];
  const float* x   = (const float*)d_in[2];
  const int*   esrc= (const int*)d_in[3];
  const int*   edst= (const int*)d_in[4];
  const float* th1 = (const float*)d_in[5];
  const float* th2 = (const float*)d_in[6];
  const float* th3 = (const float*)d_in[7];
  const float* th4 = (const float*)d_in[8];
  const float* th5 = (const float*)d_in[9];
  const float* hth = (const float*)d_in[10];
  float* out = (float*)d_out;
  const int n = in_sizes[0];
  const int e = in_sizes[3];

  char* wp = (char*)d_ws;
  auto carve = [&](size_t bytes) { char* p = wp; wp += (bytes + 255) & ~(size_t)255; return p; };
  uint*   xn    = (uint*)  carve((size_t)n*128*2);  // xn bf16; aliased as mu' later
  ushort* mu_s  = (ushort*)carve((size_t)n*128*2);  // mu bf16 row-major
  ushort* rs_s  = (ushort*)carve((size_t)n*128*2);  // relu(s) bf16 row-major
  int*    sorted= (int*)   carve((size_t)e*4);
  int*    cnt   = (int*)   carve((size_t)n*4);
  int*    excl  = (int*)   carve((size_t)n*4);
  int*    rowst = (int*)   carve((size_t)n*4);
  int*    cursor= (int*)   carve((size_t)n*4);
  int*    bsum  = (int*)   carve(512*4);
  int*    bbase = (int*)   carve(512*4);
  float*  gsum  = (float*) carve(128*4);
  float*  Cbuf  = (float*) carve(256);

  ushort* mup_s = (ushort*)xn;   // alias: xn dead after k_mu

  const int nb1 = (n + 255) >> 8;
  const int n8  = (n + 7) >> 3;

  hipMemsetAsync(cnt, 0, (size_t)n*4, stream);
  hipMemsetAsync(gsum, 0, 128*4, stream);

  k_norm    <<<1024, 256, 0, stream>>>(x, xn, n);
  k_mu      <<<1024, 256, 0, stream>>>((const uint4*)xn, sv, tv, th1, th2, mu_s, n);
  k_count   <<<(e + 255)/256, 256, 0, stream>>>(esrc, cnt, e);
  k_scan1   <<<nb1, 256, 0, stream>>>(cnt, excl, bsum, n);
  k_scan2   <<<1, 512, 0, stream>>>(bsum, bbase, nb1);
  k_initcur <<<nb1, 256, 0, stream>>>(excl, bbase, rowst, cursor, n);
  k_scatter8<<<1024, 256, 0, stream>>>(esrc, edst, cursor, sorted, e, n8);
  k_gather  <<<2048, 256, 0, stream>>>((const uint*)mu_s, sorted, cnt, rowst,
                                       (uint*)rs_s, n);
  k_mlp     <<<1024, 256, 0, stream>>>((const uint4*)mu_s, (const uint4*)rs_s,
                                       hth, mup_s, n);
  k_colsum  <<<256, 256, 0, stream>>>((const uint*)mup_s, gsum, n);
  k_upC     <<<1, 128, 0, stream>>>(gsum, th4, th3, Cbuf);
  k_final   <<<1024, 256, 0, stream>>>((const uint4*)mup_s, th5, th3, Cbuf, out, n);
}

// Round 5
// 498.674 us; speedup vs baseline: 2.3714x; 1.3990x over previous
//
#include <hip/hip_runtime.h>
#include <stdint.h>

typedef unsigned int uint;
typedef unsigned short ushort;
typedef __attribute__((ext_vector_type(4))) float f32x4;
typedef __attribute__((ext_vector_type(8))) short bf16x8;   // 8 bf16 in 4 VGPRs

union U4H8 { uint4 u; bf16x8 h; };

__device__ __forceinline__ float bflo(uint u){ return __uint_as_float(u << 16); }
__device__ __forceinline__ float bfhi(uint u){ return __uint_as_float(u & 0xffff0000u); }
__device__ __forceinline__ ushort f2bf(float f){
  uint u = __float_as_uint(f);
  return (ushort)((u + 0x7fffu + ((u >> 16) & 1u)) >> 16);   // RNE
}
__device__ __forceinline__ uint pack2(float lo, float hi){
  return ((uint)f2bf(hi) << 16) | (uint)f2bf(lo);
}

#define CHUNK 8192          // edges per partition block

// ---------------------------------------------------------------------------
// xn[v] = x[v] / ||x[v]||  -> bf16 packed row-major [N][128] (uint[N][64])
// ---------------------------------------------------------------------------
__global__ __launch_bounds__(256) void k_norm(const float* __restrict__ x,
    uint* __restrict__ xn_u, int n)
{
  int w = threadIdx.x >> 6, l = threadIdx.x & 63;
  for (int v = blockIdx.x*4 + w; v < n; v += gridDim.x*4) {
    float2 xv = ((const float2*)x)[(size_t)v*64 + l];
    float ss = xv.x*xv.x + xv.y*xv.y;
    #pragma unroll
    for (int off = 32; off > 0; off >>= 1) ss += __shfl_down(ss, off, 64);
    ss = __shfl(ss, 0, 64);
    float inv = (ss > 0.f) ? rsqrtf(ss) : 1.f;
    xn_u[(size_t)v*64 + l] = pack2(xv.x*inv, xv.y*inv);
  }
}

// ---------------------------------------------------------------------------
// MFMA GEMM #1: mu[v][p] = relu( (xn @ th2^T)[v][p] + th1[p][0]*sv + th1[p][1]*tv )
// 16x16x32 frags; D mapping: col=lane&15, row=(lane>>4)*4+reg  [m89/m91].
// ---------------------------------------------------------------------------
__global__ __launch_bounds__(256) void k_mu(
    const uint4* __restrict__ xn4, const float* __restrict__ sv,
    const float* __restrict__ tv, const float* __restrict__ th1,
    const float* __restrict__ th2, ushort* __restrict__ mu_s, int n)
{
  __shared__ uint4 B[2048];   // [s:4][t:8][lane:64], 32 KB
  const int tid = threadIdx.x;
  for (int f = tid; f < 2048; f += 256) {
    int l = f & 63, rest = f >> 6;          // rest: 0..31
    int s = rest >> 3, t = rest & 7;
    int row = t*16 + (l & 15);              // W row (output col p)
    int kb  = s*32 + (l >> 4)*8;
    const float* p = th2 + row*128 + kb;
    float4 a = *(const float4*)p;
    float4 b = *(const float4*)(p + 4);
    uint4 u; u.x = pack2(a.x,a.y); u.y = pack2(a.z,a.w);
    u.z = pack2(b.x,b.y); u.w = pack2(b.z,b.w);
    B[(s*8 + t)*64 + l] = u;
  }
  __syncthreads();
  const int w = tid >> 6, l = tid & 63, q = l >> 4, c = l & 15;
  float2 t1[8];
  #pragma unroll
  for (int t = 0; t < 8; ++t) t1[t] = ((const float2*)th1)[t*16 + c];
  const int ntiles = (n + 15) >> 4;
  for (int T = blockIdx.x*4 + w; T < ntiles; T += gridDim.x*4) {
    int v0 = T*16;
    int arow = min(v0 + c, n-1);
    U4H8 a[4];
    #pragma unroll
    for (int s = 0; s < 4; ++s) a[s].u = xn4[(size_t)arow*16 + s*4 + q];
    f32x4 acc[8];
    #pragma unroll
    for (int t = 0; t < 8; ++t) acc[t] = (f32x4){0.f,0.f,0.f,0.f};
    #pragma unroll
    for (int s = 0; s < 4; ++s) {
      #pragma unroll
      for (int t = 0; t < 8; ++t) {
        U4H8 b; b.u = B[(s*8 + t)*64 + l];
        acc[t] = __builtin_amdgcn_mfma_f32_16x16x32_bf16(a[s].h, b.h, acc[t], 0, 0, 0);
      }
    }
    float svr[4], tvr[4];
    #pragma unroll
    for (int r = 0; r < 4; ++r) {
      int node = min(v0 + q*4 + r, n-1);
      svr[r] = sv[node]; tvr[r] = tv[node];
    }
    #pragma unroll
    for (int t = 0; t < 8; ++t) {
      #pragma unroll
      for (int r = 0; r < 4; ++r) {
        int node = v0 + q*4 + r;
        if (node < n) {
          float m = fmaxf(acc[t][r] + t1[t].x*svr[r] + t1[t].y*tvr[r], 0.f);
          mu_s[(size_t)node*128 + t*16 + c] = f2bf(m);
        }
      }
    }
  }
}

// --------------------- CSR build: 2-phase bucket partition ------------------
// bucket = src>>9 (512 nodes, ~16k edges, 64 KB window). NO global atomics:
// per-block ranking via histogram + scan (round-3 lesson: low-cardinality
// global atomic cursors serialize at ~183 ns/op; round-4 lesson: %8 block
// grouping gives no physical XCD locality).

// per-block 256-bucket histogram of its CHUNK of edges
__global__ __launch_bounds__(256) void k_hist(const int* __restrict__ src,
    int* __restrict__ histG, int e, int nblk)
{
  __shared__ int lh[256];
  const int blk = blockIdx.x, tid = threadIdx.x;
  lh[tid] = 0; __syncthreads();
  const int lo = blk*CHUNK, hi = min(e, lo + CHUNK);
  for (int i = lo + tid; i < hi; i += 256)
    atomicAdd(&lh[src[i] >> 9], 1);
  __syncthreads();
  histG[tid*nblk + blk] = lh[tid];   // layout [bucket][block]
}

// per-bucket exclusive scan across blocks; emits bucket totals
__global__ __launch_bounds__(512) void k_scanH(int* __restrict__ histG,
    int* __restrict__ bucketTot, int nblk)
{
  __shared__ int tmp[512];
  const int b = blockIdx.x, tid = threadIdx.x;
  int v = (tid < nblk) ? histG[b*nblk + tid] : 0;
  tmp[tid] = v; __syncthreads();
  for (int off = 1; off < 512; off <<= 1) {
    int t = (tid >= off) ? tmp[tid - off] : 0;
    __syncthreads();
    tmp[tid] += t;
    __syncthreads();
  }
  if (tid < nblk) histG[b*nblk + tid] = tmp[tid] - v;   // exclusive
  if (tid == nblk - 1) bucketTot[b] = tmp[tid];
}

// exclusive scan of 256 bucket totals -> bucketBase
__global__ __launch_bounds__(256) void k_scanB(const int* __restrict__ bucketTot,
    int* __restrict__ bucketBase)
{
  __shared__ int tmp[256];
  int tid = threadIdx.x;
  int v = bucketTot[tid];
  tmp[tid] = v; __syncthreads();
  for (int off = 1; off < 256; off <<= 1) {
    int t = (tid >= off) ? tmp[tid - off] : 0;
    __syncthreads();
    tmp[tid] += t;
    __syncthreads();
  }
  bucketBase[tid] = tmp[tid] - v;
}

// re-read chunk, write packed entries at precomputed positions:
// 256 sequential per-bucket streams per block (line-accumulating writes)
__global__ __launch_bounds__(256) void k_part(
    const int* __restrict__ src, const int* __restrict__ dst,
    const int* __restrict__ histG, const int* __restrict__ bucketBase,
    uint* __restrict__ packed, int e, int nblk)
{
  __shared__ int cur[256];
  const int blk = blockIdx.x, tid = threadIdx.x;
  cur[tid] = bucketBase[tid] + histG[tid*nblk + blk];
  __syncthreads();
  const int lo = blk*CHUNK, hi = min(e, lo + CHUNK);
  for (int i = lo + tid; i < hi; i += 256) {
    int s = src[i], d = dst[i];
    int pos = atomicAdd(&cur[s >> 9], 1);
    packed[pos] = ((uint)(s & 511) << 17) | (uint)d;
  }
}

// one block per bucket: local hist+scan -> cnt/rowstart, scatter into the
// bucket's contiguous 64 KB window (single block => single XCD => L2-local)
__global__ __launch_bounds__(512) void k_csr(
    const uint* __restrict__ packed, const int* __restrict__ bucketTot,
    const int* __restrict__ bucketBase, int* __restrict__ sorted,
    int* __restrict__ rowstart, int* __restrict__ cnt, int n)
{
  __shared__ int lc[512];
  __shared__ int lofs[512];
  __shared__ int lcur[512];
  const int b = blockIdx.x, tid = threadIdx.x;
  const int base = bucketBase[b], tot = bucketTot[b];
  lc[tid] = 0; __syncthreads();
  for (int i = tid; i < tot; i += 512)
    atomicAdd(&lc[packed[base + i] >> 17], 1);
  __syncthreads();
  lofs[tid] = lc[tid]; __syncthreads();
  for (int off = 1; off < 512; off <<= 1) {
    int t = (tid >= off) ? lofs[tid - off] : 0;
    __syncthreads();
    lofs[tid] += t;
    __syncthreads();
  }
  int excl = lofs[tid] - lc[tid];
  int node = (b << 9) + tid;
  lcur[tid] = base + excl;
  if (node < n) { rowstart[node] = base + excl; cnt[node] = lc[tid]; }
  __syncthreads();
  for (int i = tid; i < tot; i += 512) {
    uint p = packed[base + i];
    int pos = atomicAdd(&lcur[p >> 17], 1);
    sorted[pos] = (int)(p & 0x1FFFFu);
  }
}

// ---------------------------------------------------------------------------
// Gather: rs[v] = relu(deg*mu[v] - sum_{u in N(v)} mu[u])  bf16 [N][128]
// Zero LDS (full occupancy); 8 independent row-loads in flight per batch.
// ---------------------------------------------------------------------------
__global__ __launch_bounds__(256) void k_gather(
    const uint* __restrict__ mu_u, const int* __restrict__ sorted,
    const int* __restrict__ cnt, const int* __restrict__ rowstart,
    uint* __restrict__ rs_u, int n)
{
  int w = threadIdx.x >> 6, l = threadIdx.x & 63;
  for (int v = blockIdx.x*4 + w; v < n; v += gridDim.x*4) {
    int deg = cnt[v], start = rowstart[v];
    float nb0 = 0.f, nb1 = 0.f;
    for (int base = 0; base < deg; base += 64) {
      int m = min(deg - base, 64);
      int idx = (l < m) ? sorted[start + base + l] : 0;
      int j = 0;
      for (; j + 8 <= m; j += 8) {
        uint u0 = mu_u[(size_t)__shfl(idx, j+0, 64)*64 + l];
        uint u1 = mu_u[(size_t)__shfl(idx, j+1, 64)*64 + l];
        uint u2 = mu_u[(size_t)__shfl(idx, j+2, 64)*64 + l];
        uint u3 = mu_u[(size_t)__shfl(idx, j+3, 64)*64 + l];
        uint u4 = mu_u[(size_t)__shfl(idx, j+4, 64)*64 + l];
        uint u5 = mu_u[(size_t)__shfl(idx, j+5, 64)*64 + l];
        uint u6 = mu_u[(size_t)__shfl(idx, j+6, 64)*64 + l];
        uint u7 = mu_u[(size_t)__shfl(idx, j+7, 64)*64 + l];
        nb0 += (bflo(u0)+bflo(u1)) + (bflo(u2)+bflo(u3))
             + (bflo(u4)+bflo(u5)) + (bflo(u6)+bflo(u7));
        nb1 += (bfhi(u0)+bfhi(u1)) + (bfhi(u2)+bfhi(u3))
             + (bfhi(u4)+bfhi(u5)) + (bfhi(u6)+bfhi(u7));
      }
      for (; j < m; ++j) {
        uint u = mu_u[(size_t)__shfl(idx, j, 64)*64 + l];
        nb0 += bflo(u); nb1 += bfhi(u);
      }
    }
    uint um = mu_u[(size_t)v*64 + l];
    float dg = (float)deg;
    float s0 = fmaxf(dg*bflo(um) - nb0, 0.f);
    float s1 = fmaxf(dg*bfhi(um) - nb1, 0.f);
    rs_u[(size_t)v*64 + l] = pack2(s0, s1);
  }
}

// ---------------------------------------------------------------------------
// MFMA GEMM #2: mu'[v] = [mu ; relu(s)] @ h_theta^T   (K=256)
// ---------------------------------------------------------------------------
__global__ __launch_bounds__(256) void k_mlp(
    const uint4* __restrict__ mu4, const uint4* __restrict__ rs4,
    const float* __restrict__ hth, ushort* __restrict__ mup_s, int n)
{
  __shared__ uint4 B[4096];   // [s:8][t:8][lane:64], 64 KB
  const int tid = threadIdx.x;
  for (int f = tid; f < 4096; f += 256) {
    int l = f & 63, rest = f >> 6;          // 0..63
    int s = rest >> 3, t = rest & 7;
    int row = t*16 + (l & 15);
    int kb  = s*32 + (l >> 4)*8;
    const float* p = hth + row*256 + kb;
    float4 a = *(const float4*)p;
    float4 b = *(const float4*)(p + 4);
    uint4 u; u.x = pack2(a.x,a.y); u.y = pack2(a.z,a.w);
    u.z = pack2(b.x,b.y); u.w = pack2(b.z,b.w);
    B[(s*8 + t)*64 + l] = u;
  }
  __syncthreads();
  const int w = tid >> 6, l = tid & 63, q = l >> 4, c = l & 15;
  const int ntiles = (n + 15) >> 4;
  for (int T = blockIdx.x*4 + w; T < ntiles; T += gridDim.x*4) {
    int v0 = T*16;
    int arow = min(v0 + c, n-1);
    U4H8 a[8];
    #pragma unroll
    for (int s = 0; s < 4; ++s) a[s].u   = mu4[(size_t)arow*16 + s*4 + q];
    #pragma unroll
    for (int s = 0; s < 4; ++s) a[4+s].u = rs4[(size_t)arow*16 + s*4 + q];
    f32x4 acc[8];
    #pragma unroll
    for (int t = 0; t < 8; ++t) acc[t] = (f32x4){0.f,0.f,0.f,0.f};
    #pragma unroll
    for (int s = 0; s < 8; ++s) {
      #pragma unroll
      for (int t = 0; t < 8; ++t) {
        U4H8 b; b.u = B[(s*8 + t)*64 + l];
        acc[t] = __builtin_amdgcn_mfma_f32_16x16x32_bf16(a[s].h, b.h, acc[t], 0, 0, 0);
      }
    }
    #pragma unroll
    for (int t = 0; t < 8; ++t) {
      #pragma unroll
      for (int r = 0; r < 4; ++r) {
        int node = v0 + q*4 + r;
        if (node < n) mup_s[(size_t)node*128 + t*16 + c] = f2bf(acc[t][r]);
      }
    }
  }
}

// column sums of mu' -> gsum[128]
__global__ __launch_bounds__(256) void k_colsum(const uint* __restrict__ mup_u,
    float* __restrict__ gsum, int n) {
  int w = threadIdx.x >> 6, l = threadIdx.x & 63;
  float a0 = 0.f, a1 = 0.f;
  for (int v = blockIdx.x*4 + w; v < n; v += gridDim.x*4) {
    uint u = mup_u[(size_t)v*64 + l];
    a0 += bflo(u); a1 += bfhi(u);
  }
  atomicAdd(&gsum[2*l],   a0);
  atomicAdd(&gsum[2*l+1], a1);
}

// up = th4 @ gsum; C = sum_p th3[p]*relu(up[p])
__global__ __launch_bounds__(128) void k_upC(const float* __restrict__ gsum,
    const float* __restrict__ th4, const float* __restrict__ th3,
    float* __restrict__ Cbuf) {
  __shared__ float S[128];
  __shared__ float part[128];
  int tid = threadIdx.x;
  S[tid] = gsum[tid];
  __syncthreads();
  float up = 0.f;
  const float4* r4 = (const float4*)(th4 + tid*128);
  const float4* S4 = (const float4*)S;
  #pragma unroll 8
  for (int qq = 0; qq < 32; ++qq) {
    float4 wv = r4[qq], av = S4[qq];
    up += wv.x*av.x + wv.y*av.y + wv.z*av.z + wv.w*av.w;
  }
  float r = th3[tid] * fmaxf(up, 0.f);
  part[tid] = r; __syncthreads();
  if (tid < 64) part[tid] += part[tid + 64];
  __syncthreads();
  if (tid < 64) {
    float v = part[tid];
    #pragma unroll
    for (int off = 32; off > 0; off >>= 1) v += __shfl_down(v, off, 64);
    if (tid == 0) Cbuf[0] = v;
  }
}

// ---------------------------------------------------------------------------
// MFMA GEMM #3 + epilogue: out[v] = C + sum_p th3[128+p]*relu((mu' @ th5^T)[v][p])
// ---------------------------------------------------------------------------
__global__ __launch_bounds__(256) void k_final(
    const uint4* __restrict__ mup4, const float* __restrict__ th5,
    const float* __restrict__ th3, const float* __restrict__ Cbuf,
    float* __restrict__ out, int n)
{
  __shared__ uint4 B[2048];   // 32 KB
  const int tid = threadIdx.x;
  for (int f = tid; f < 2048; f += 256) {
    int l = f & 63, rest = f >> 6;
    int s = rest >> 3, t = rest & 7;
    int row = t*16 + (l & 15);
    int kb  = s*32 + (l >> 4)*8;
    const float* p = th5 + row*128 + kb;
    float4 a = *(const float4*)p;
    float4 b = *(const float4*)(p + 4);
    uint4 u; u.x = pack2(a.x,a.y); u.y = pack2(a.z,a.w);
    u.z = pack2(b.x,b.y); u.w = pack2(b.z,b.w);
    B[(s*8 + t)*64 + l] = u;
  }
  __syncthreads();
  const int w = tid >> 6, l = tid & 63, q = l >> 4, c = l & 15;
  float t3w[8];
  #pragma unroll
  for (int t = 0; t < 8; ++t) t3w[t] = th3[128 + t*16 + c];
  const float C = Cbuf[0];
  const int ntiles = (n + 15) >> 4;
  for (int T = blockIdx.x*4 + w; T < ntiles; T += gridDim.x*4) {
    int v0 = T*16;
    int arow = min(v0 + c, n-1);
    U4H8 a[4];
    #pragma unroll
    for (int s = 0; s < 4; ++s) a[s].u = mup4[(size_t)arow*16 + s*4 + q];
    f32x4 acc[8];
    #pragma unroll
    for (int t = 0; t < 8; ++t) acc[t] = (f32x4){0.f,0.f,0.f,0.f};
    #pragma unroll
    for (int s = 0; s < 4; ++s) {
      #pragma unroll
      for (int t = 0; t < 8; ++t) {
        U4H8 b; b.u = B[(s*8 + t)*64 + l];
        acc[t] = __builtin_amdgcn_mfma_f32_16x16x32_bf16(a[s].h, b.h, acc[t], 0, 0, 0);
      }
    }
    float red[4] = {0.f, 0.f, 0.f, 0.f};
    #pragma unroll
    for (int t = 0; t < 8; ++t) {
      #pragma unroll
      for (int r = 0; r < 4; ++r)
        red[r] += t3w[t] * fmaxf(acc[t][r], 0.f);
    }
    #pragma unroll
    for (int r = 0; r < 4; ++r) {
      #pragma unroll
      for (int off = 1; off < 16; off <<= 1)
        red[r] += __shfl_xor(red[r], off, 64);
    }
    if (c == 0) {
      #pragma unroll
      for (int r = 0; r < 4; ++r) {
        int node = v0 + q*4 + r;
        if (node < n) out[node] = C + red[r];
      }
    }
  }
}

extern "C" void kernel_launch(void* const* d_in, const int* in_sizes, int n_in,
                              void* d_out, int out_size, void* d_ws, size_t ws_size,
                              hipStream_t stream)
{
  const float* sv  = (const float*)d_in[0];
  const float* tv  = (const float*)d_in[1];
  const float* x   = (const float*)d_in[2];
  const int*   esrc= (const int*)d_in[3];
  const int*   edst= (const int*)d_in[4];
  const float* th1 = (const float*)d_in[5];
  const float* th2 = (const float*)d_in[6];
  const float* th3 = (const float*)d_in[7];
  const float* th4 = (const float*)d_in[8];
  const float* th5 = (const float*)d_in[9];
  const float* hth = (const float*)d_in[10];
  float* out = (float*)d_out;
  const int n = in_sizes[0];
  const int e = in_sizes[3];

  const int nblk  = (e + CHUNK - 1) / CHUNK;     // 391 partition blocks
  const int nbuck = (n + 511) >> 9;              // 196 buckets

  char* wp = (char*)d_ws;
  auto carve = [&](size_t bytes) { char* p = wp; wp += (bytes + 255) & ~(size_t)255; return p; };
  uint*   xn    = (uint*)  carve((size_t)n*128*2);  // R1: xn -> packed -> mu' (aliased)
  ushort* mu_s  = (ushort*)carve((size_t)n*128*2);  // mu bf16 row-major
  ushort* rs_s  = (ushort*)carve((size_t)n*128*2);  // relu(s) bf16 row-major
  int*    sorted= (int*)   carve((size_t)e*4);
  int*    cnt   = (int*)   carve((size_t)n*4);
  int*    rowst = (int*)   carve((size_t)n*4);
  int*    histG = (int*)   carve((size_t)256*nblk*4);
  int*    btot  = (int*)   carve(256*4);
  int*    bbase = (int*)   carve(256*4);
  float*  gsum  = (float*) carve(128*4);
  float*  Cbuf  = (float*) carve(256);

  uint*   packed= (uint*)xn;     // alias: xn dead after k_mu, packed dead before k_mlp
  ushort* mup_s = (ushort*)xn;   // alias: mu' written after packed is consumed

  hipMemsetAsync(gsum, 0, 128*4, stream);

  k_norm  <<<1024, 256, 0, stream>>>(x, xn, n);
  k_mu    <<<1024, 256, 0, stream>>>((const uint4*)xn, sv, tv, th1, th2, mu_s, n);
  k_hist  <<<nblk, 256, 0, stream>>>(esrc, histG, e, nblk);
  k_scanH <<<256, 512, 0, stream>>>(histG, btot, nblk);
  k_scanB <<<1, 256, 0, stream>>>(btot, bbase);
  k_part  <<<nblk, 256, 0, stream>>>(esrc, edst, histG, bbase, packed, e, nblk);
  k_csr   <<<nbuck, 512, 0, stream>>>(packed, btot, bbase, sorted, rowst, cnt, n);
  k_gather<<<2048, 256, 0, stream>>>((const uint*)mu_s, sorted, cnt, rowst,
                                     (uint*)rs_s, n);
  k_mlp   <<<1024, 256, 0, stream>>>((const uint4*)mu_s, (const uint4*)rs_s,
                                     hth, mup_s, n);
  k_colsum<<<256, 256, 0, stream>>>((const uint*)mup_s, gsum, n);
  k_upC   <<<1, 128, 0, stream>>>(gsum, th4, th3, Cbuf);
  k_final <<<1024, 256, 0, stream>>>((const uint4*)mup_s, th5, th3, Cbuf, out, n);
}

// Round 6
// 485.037 us; speedup vs baseline: 2.4380x; 1.0281x over previous
//
#include <hip/hip_runtime.h>
#include <stdint.h>

typedef unsigned int uint;
typedef unsigned short ushort;
typedef __attribute__((ext_vector_type(4))) float f32x4;
typedef __attribute__((ext_vector_type(8))) short bf16x8;   // 8 bf16 in 4 VGPRs

union U4H8 { uint4 u; bf16x8 h; };

__device__ __forceinline__ float bflo(uint u){ return __uint_as_float(u << 16); }
__device__ __forceinline__ float bfhi(uint u){ return __uint_as_float(u & 0xffff0000u); }
__device__ __forceinline__ ushort f2bf(float f){
  uint u = __float_as_uint(f);
  return (ushort)((u + 0x7fffu + ((u >> 16) & 1u)) >> 16);   // RNE
}
__device__ __forceinline__ uint pack2(float lo, float hi){
  return ((uint)f2bf(hi) << 16) | (uint)f2bf(lo);
}

#define CHUNK 8192          // edges per partition block

// ---------------------------------------------------------------------------
// MFMA GEMM #1 (norm fused): mu[v][p] = relu((x/||x|| @ th2^T) + th1 conn)
// A-frag lanes load x f32 directly; row-norm via shfl_xor(16,32) since the
// 4 lanes sharing (l&15) jointly hold the whole 128-elem row.
// D mapping: col=lane&15, row=(lane>>4)*4+reg  [m89/m91].
// ---------------------------------------------------------------------------
__global__ __launch_bounds__(256) void k_mu(
    const float* __restrict__ x, const float* __restrict__ sv,
    const float* __restrict__ tv, const float* __restrict__ th1,
    const float* __restrict__ th2, ushort* __restrict__ mu_s, int n)
{
  __shared__ uint4 B[2048];   // [s:4][t:8][lane:64], 32 KB
  const int tid = threadIdx.x;
  for (int f = tid; f < 2048; f += 256) {
    int l = f & 63, rest = f >> 6;          // rest: 0..31
    int s = rest >> 3, t = rest & 7;
    int row = t*16 + (l & 15);              // W row (output col p)
    int kb  = s*32 + (l >> 4)*8;
    const float* p = th2 + row*128 + kb;
    float4 a = *(const float4*)p;
    float4 b = *(const float4*)(p + 4);
    uint4 u; u.x = pack2(a.x,a.y); u.y = pack2(a.z,a.w);
    u.z = pack2(b.x,b.y); u.w = pack2(b.z,b.w);
    B[(s*8 + t)*64 + l] = u;
  }
  __syncthreads();
  const int w = tid >> 6, l = tid & 63, q = l >> 4, c = l & 15;
  float2 t1[8];
  #pragma unroll
  for (int t = 0; t < 8; ++t) t1[t] = ((const float2*)th1)[t*16 + c];
  const int ntiles = (n + 15) >> 4;
  for (int T = blockIdx.x*4 + w; T < ntiles; T += gridDim.x*4) {
    int v0 = T*16;
    int arow = min(v0 + c, n-1);
    const float4* xr = (const float4*)(x + (size_t)arow*128);
    float4 xf[8];
    #pragma unroll
    for (int s = 0; s < 4; ++s) {
      xf[2*s]   = xr[s*8 + q*2];
      xf[2*s+1] = xr[s*8 + q*2 + 1];
    }
    float ss = 0.f;
    #pragma unroll
    for (int i = 0; i < 8; ++i)
      ss += xf[i].x*xf[i].x + xf[i].y*xf[i].y + xf[i].z*xf[i].z + xf[i].w*xf[i].w;
    ss += __shfl_xor(ss, 16, 64);
    ss += __shfl_xor(ss, 32, 64);
    float inv = (ss > 0.f) ? rsqrtf(ss) : 1.f;
    U4H8 a[4];
    #pragma unroll
    for (int s = 0; s < 4; ++s) {
      float4 u0 = xf[2*s], u1 = xf[2*s+1];
      a[s].u = make_uint4(pack2(u0.x*inv, u0.y*inv), pack2(u0.z*inv, u0.w*inv),
                          pack2(u1.x*inv, u1.y*inv), pack2(u1.z*inv, u1.w*inv));
    }
    f32x4 acc[8];
    #pragma unroll
    for (int t = 0; t < 8; ++t) acc[t] = (f32x4){0.f,0.f,0.f,0.f};
    #pragma unroll
    for (int s = 0; s < 4; ++s) {
      #pragma unroll
      for (int t = 0; t < 8; ++t) {
        U4H8 b; b.u = B[(s*8 + t)*64 + l];
        acc[t] = __builtin_amdgcn_mfma_f32_16x16x32_bf16(a[s].h, b.h, acc[t], 0, 0, 0);
      }
    }
    float svr[4], tvr[4];
    #pragma unroll
    for (int r = 0; r < 4; ++r) {
      int node = min(v0 + q*4 + r, n-1);
      svr[r] = sv[node]; tvr[r] = tv[node];
    }
    #pragma unroll
    for (int t = 0; t < 8; ++t) {
      #pragma unroll
      for (int r = 0; r < 4; ++r) {
        int node = v0 + q*4 + r;
        if (node < n) {
          float m = fmaxf(acc[t][r] + t1[t].x*svr[r] + t1[t].y*tvr[r], 0.f);
          mu_s[(size_t)node*128 + t*16 + c] = f2bf(m);
        }
      }
    }
  }
}

// --------------------- CSR build: 2-phase bucket partition ------------------
// bucket = src>>9. Per-block ranking via LDS histogram + scan; no global
// atomic cursors (round-3: contended device atomics ~183 ns/op/address).

__global__ __launch_bounds__(256) void k_hist(const int* __restrict__ src,
    int* __restrict__ histG, int e, int nblk)
{
  __shared__ int lh[256];
  const int blk = blockIdx.x, tid = threadIdx.x;
  lh[tid] = 0; __syncthreads();
  const int lo = blk*CHUNK, hi = min(e, lo + CHUNK);
  for (int i = lo + tid; i < hi; i += 256)
    atomicAdd(&lh[src[i] >> 9], 1);
  __syncthreads();
  histG[tid*nblk + blk] = lh[tid];   // layout [bucket][block]
}

__global__ __launch_bounds__(512) void k_scanH(int* __restrict__ histG,
    int* __restrict__ bucketTot, int nblk)
{
  __shared__ int tmp[512];
  const int b = blockIdx.x, tid = threadIdx.x;
  int v = (tid < nblk) ? histG[b*nblk + tid] : 0;
  tmp[tid] = v; __syncthreads();
  for (int off = 1; off < 512; off <<= 1) {
    int t = (tid >= off) ? tmp[tid - off] : 0;
    __syncthreads();
    tmp[tid] += t;
    __syncthreads();
  }
  if (tid < nblk) histG[b*nblk + tid] = tmp[tid] - v;   // exclusive
  if (tid == nblk - 1) bucketTot[b] = tmp[tid];
}

__global__ __launch_bounds__(256) void k_scanB(const int* __restrict__ bucketTot,
    int* __restrict__ bucketBase)
{
  __shared__ int tmp[256];
  int tid = threadIdx.x;
  int v = bucketTot[tid];
  tmp[tid] = v; __syncthreads();
  for (int off = 1; off < 256; off <<= 1) {
    int t = (tid >= off) ? tmp[tid - off] : 0;
    __syncthreads();
    tmp[tid] += t;
    __syncthreads();
  }
  bucketBase[tid] = tmp[tid] - v;
}

__global__ __launch_bounds__(256) void k_part(
    const int* __restrict__ src, const int* __restrict__ dst,
    const int* __restrict__ histG, const int* __restrict__ bucketBase,
    uint* __restrict__ packed, int e, int nblk)
{
  __shared__ int cur[256];
  const int blk = blockIdx.x, tid = threadIdx.x;
  cur[tid] = bucketBase[tid] + histG[tid*nblk + blk];
  __syncthreads();
  const int lo = blk*CHUNK, hi = min(e, lo + CHUNK);
  for (int i = lo + tid; i < hi; i += 256) {
    int s = src[i], d = dst[i];
    int pos = atomicAdd(&cur[s >> 9], 1);
    packed[pos] = ((uint)(s & 511) << 17) | (uint)d;
  }
}

__global__ __launch_bounds__(512) void k_csr(
    const uint* __restrict__ packed, const int* __restrict__ bucketTot,
    const int* __restrict__ bucketBase, int* __restrict__ sorted,
    int* __restrict__ rowstart, int* __restrict__ cnt, int n)
{
  __shared__ int lc[512];
  __shared__ int lofs[512];
  __shared__ int lcur[512];
  const int b = blockIdx.x, tid = threadIdx.x;
  const int base = bucketBase[b], tot = bucketTot[b];
  lc[tid] = 0; __syncthreads();
  for (int i = tid; i < tot; i += 512)
    atomicAdd(&lc[packed[base + i] >> 17], 1);
  __syncthreads();
  lofs[tid] = lc[tid]; __syncthreads();
  for (int off = 1; off < 512; off <<= 1) {
    int t = (tid >= off) ? lofs[tid - off] : 0;
    __syncthreads();
    lofs[tid] += t;
    __syncthreads();
  }
  int excl = lofs[tid] - lc[tid];
  int node = (b << 9) + tid;
  lcur[tid] = base + excl;
  if (node < n) { rowstart[node] = base + excl; cnt[node] = lc[tid]; }
  __syncthreads();
  for (int i = tid; i < tot; i += 512) {
    uint p = packed[base + i];
    int pos = atomicAdd(&lcur[p >> 17], 1);
    sorted[pos] = (int)(p & 0x1FFFFu);
  }
}

// ---------------------------------------------------------------------------
// Gather: rs[v] = relu(deg*mu[v] - sum_{u in N(v)} mu[u])
// uint4 loads: lane l = edge subgroup g=l>>4, feature chunk c=l&15 (16 B).
// One wave-load covers 4 edges (1 KB/instr); combine groups via shfl_xor.
// ---------------------------------------------------------------------------
__global__ __launch_bounds__(256) void k_gather(
    const uint4* __restrict__ mu4, const int* __restrict__ sorted,
    const int* __restrict__ cnt, const int* __restrict__ rowstart,
    uint4* __restrict__ rs4, int n)
{
  const int w = threadIdx.x >> 6, l = threadIdx.x & 63;
  const int g = l >> 4, c = l & 15;
  for (int v = blockIdx.x*4 + w; v < n; v += gridDim.x*4) {
    int deg = cnt[v], start = rowstart[v];
    float acc[8] = {0.f,0.f,0.f,0.f,0.f,0.f,0.f,0.f};
    for (int base = 0; base < deg; base += 64) {
      int m = min(deg - base, 64);
      int idx = (l < m) ? sorted[start + base + l] : 0;
      int full = m & ~3;
      #pragma unroll 4
      for (int j = 0; j < full; j += 4) {
        int d = __shfl(idx, j + g, 64);
        uint4 u = mu4[(size_t)d*16 + c];
        acc[0] += bflo(u.x); acc[1] += bfhi(u.x);
        acc[2] += bflo(u.y); acc[3] += bfhi(u.y);
        acc[4] += bflo(u.z); acc[5] += bfhi(u.z);
        acc[6] += bflo(u.w); acc[7] += bfhi(u.w);
      }
      int rem = m - full;
      if (rem) {
        int d = __shfl(idx, full + min(g, rem-1), 64);
        uint4 u = mu4[(size_t)d*16 + c];
        if (g < rem) {
          acc[0] += bflo(u.x); acc[1] += bfhi(u.x);
          acc[2] += bflo(u.y); acc[3] += bfhi(u.y);
          acc[4] += bflo(u.z); acc[5] += bfhi(u.z);
          acc[6] += bflo(u.w); acc[7] += bfhi(u.w);
        }
      }
    }
    #pragma unroll
    for (int i = 0; i < 8; ++i) {
      acc[i] += __shfl_xor(acc[i], 16, 64);
      acc[i] += __shfl_xor(acc[i], 32, 64);
    }
    if (g == 0) {
      uint4 um = mu4[(size_t)v*16 + c];
      float dg = (float)deg;
      uint4 o;
      o.x = pack2(fmaxf(dg*bflo(um.x) - acc[0], 0.f), fmaxf(dg*bfhi(um.x) - acc[1], 0.f));
      o.y = pack2(fmaxf(dg*bflo(um.y) - acc[2], 0.f), fmaxf(dg*bfhi(um.y) - acc[3], 0.f));
      o.z = pack2(fmaxf(dg*bflo(um.z) - acc[4], 0.f), fmaxf(dg*bfhi(um.z) - acc[5], 0.f));
      o.w = pack2(fmaxf(dg*bflo(um.w) - acc[6], 0.f), fmaxf(dg*bfhi(um.w) - acc[7], 0.f));
      rs4[(size_t)v*16 + c] = o;
    }
  }
}

// ---------------------------------------------------------------------------
// MFMA GEMM #2: mu'[v] = [mu ; relu(s)] @ h_theta^T   (K=256)
// ---------------------------------------------------------------------------
__global__ __launch_bounds__(256) void k_mlp(
    const uint4* __restrict__ mu4, const uint4* __restrict__ rs4,
    const float* __restrict__ hth, ushort* __restrict__ mup_s, int n)
{
  __shared__ uint4 B[4096];   // [s:8][t:8][lane:64], 64 KB
  const int tid = threadIdx.x;
  for (int f = tid; f < 4096; f += 256) {
    int l = f & 63, rest = f >> 6;          // 0..63
    int s = rest >> 3, t = rest & 7;
    int row = t*16 + (l & 15);
    int kb  = s*32 + (l >> 4)*8;
    const float* p = hth + row*256 + kb;
    float4 a = *(const float4*)p;
    float4 b = *(const float4*)(p + 4);
    uint4 u; u.x = pack2(a.x,a.y); u.y = pack2(a.z,a.w);
    u.z = pack2(b.x,b.y); u.w = pack2(b.z,b.w);
    B[(s*8 + t)*64 + l] = u;
  }
  __syncthreads();
  const int w = tid >> 6, l = tid & 63, q = l >> 4, c = l & 15;
  const int ntiles = (n + 15) >> 4;
  for (int T = blockIdx.x*4 + w; T < ntiles; T += gridDim.x*4) {
    int v0 = T*16;
    int arow = min(v0 + c, n-1);
    U4H8 a[8];
    #pragma unroll
    for (int s = 0; s < 4; ++s) a[s].u   = mu4[(size_t)arow*16 + s*4 + q];
    #pragma unroll
    for (int s = 0; s < 4; ++s) a[4+s].u = rs4[(size_t)arow*16 + s*4 + q];
    f32x4 acc[8];
    #pragma unroll
    for (int t = 0; t < 8; ++t) acc[t] = (f32x4){0.f,0.f,0.f,0.f};
    #pragma unroll
    for (int s = 0; s < 8; ++s) {
      #pragma unroll
      for (int t = 0; t < 8; ++t) {
        U4H8 b; b.u = B[(s*8 + t)*64 + l];
        acc[t] = __builtin_amdgcn_mfma_f32_16x16x32_bf16(a[s].h, b.h, acc[t], 0, 0, 0);
      }
    }
    #pragma unroll
    for (int t = 0; t < 8; ++t) {
      #pragma unroll
      for (int r = 0; r < 4; ++r) {
        int node = v0 + q*4 + r;
        if (node < n) mup_s[(size_t)node*128 + t*16 + c] = f2bf(acc[t][r]);
      }
    }
  }
}

// column partial sums of mu' -> part[blockIdx][128]  (NO atomics)
__global__ __launch_bounds__(256) void k_colsum(const uint* __restrict__ mup_u,
    float* __restrict__ part, int n) {
  __shared__ float ls[4*128];
  int w = threadIdx.x >> 6, l = threadIdx.x & 63;
  float a0 = 0.f, a1 = 0.f;
  for (int v = blockIdx.x*4 + w; v < n; v += gridDim.x*4) {
    uint u = mup_u[(size_t)v*64 + l];
    a0 += bflo(u); a1 += bfhi(u);
  }
  ls[w*128 + 2*l]   = a0;
  ls[w*128 + 2*l+1] = a1;
  __syncthreads();
  int tid = threadIdx.x;
  if (tid < 128)
    part[(size_t)blockIdx.x*128 + tid] = ls[tid] + ls[128+tid] + ls[256+tid] + ls[384+tid];
}

// reduce partials -> gsum; up = th4 @ gsum; C = sum_p th3[p]*relu(up[p])
__global__ __launch_bounds__(128) void k_upC(const float* __restrict__ part,
    int npart, const float* __restrict__ th4, const float* __restrict__ th3,
    float* __restrict__ Cbuf) {
  __shared__ float S[128];
  __shared__ float pr[128];
  int tid = threadIdx.x;
  float gs = 0.f;
  for (int b = 0; b < npart; ++b) gs += part[(size_t)b*128 + tid];
  S[tid] = gs;
  __syncthreads();
  float up = 0.f;
  const float4* r4 = (const float4*)(th4 + tid*128);
  const float4* S4 = (const float4*)S;
  #pragma unroll 8
  for (int qq = 0; qq < 32; ++qq) {
    float4 wv = r4[qq], av = S4[qq];
    up += wv.x*av.x + wv.y*av.y + wv.z*av.z + wv.w*av.w;
  }
  float r = th3[tid] * fmaxf(up, 0.f);
  pr[tid] = r; __syncthreads();
  if (tid < 64) pr[tid] += pr[tid + 64];
  __syncthreads();
  if (tid < 64) {
    float v = pr[tid];
    #pragma unroll
    for (int off = 32; off > 0; off >>= 1) v += __shfl_down(v, off, 64);
    if (tid == 0) Cbuf[0] = v;
  }
}

// ---------------------------------------------------------------------------
// MFMA GEMM #3 + epilogue: out[v] = C + sum_p th3[128+p]*relu((mu' @ th5^T)[v][p])
// ---------------------------------------------------------------------------
__global__ __launch_bounds__(256) void k_final(
    const uint4* __restrict__ mup4, const float* __restrict__ th5,
    const float* __restrict__ th3, const float* __restrict__ Cbuf,
    float* __restrict__ out, int n)
{
  __shared__ uint4 B[2048];   // 32 KB
  const int tid = threadIdx.x;
  for (int f = tid; f < 2048; f += 256) {
    int l = f & 63, rest = f >> 6;
    int s = rest >> 3, t = rest & 7;
    int row = t*16 + (l & 15);
    int kb  = s*32 + (l >> 4)*8;
    const float* p = th5 + row*128 + kb;
    float4 a = *(const float4*)p;
    float4 b = *(const float4*)(p + 4);
    uint4 u; u.x = pack2(a.x,a.y); u.y = pack2(a.z,a.w);
    u.z = pack2(b.x,b.y); u.w = pack2(b.z,b.w);
    B[(s*8 + t)*64 + l] = u;
  }
  __syncthreads();
  const int w = tid >> 6, l = tid & 63, q = l >> 4, c = l & 15;
  float t3w[8];
  #pragma unroll
  for (int t = 0; t < 8; ++t) t3w[t] = th3[128 + t*16 + c];
  const float C = Cbuf[0];
  const int ntiles = (n + 15) >> 4;
  for (int T = blockIdx.x*4 + w; T < ntiles; T += gridDim.x*4) {
    int v0 = T*16;
    int arow = min(v0 + c, n-1);
    U4H8 a[4];
    #pragma unroll
    for (int s = 0; s < 4; ++s) a[s].u = mup4[(size_t)arow*16 + s*4 + q];
    f32x4 acc[8];
    #pragma unroll
    for (int t = 0; t < 8; ++t) acc[t] = (f32x4){0.f,0.f,0.f,0.f};
    #pragma unroll
    for (int s = 0; s < 4; ++s) {
      #pragma unroll
      for (int t = 0; t < 8; ++t) {
        U4H8 b; b.u = B[(s*8 + t)*64 + l];
        acc[t] = __builtin_amdgcn_mfma_f32_16x16x32_bf16(a[s].h, b.h, acc[t], 0, 0, 0);
      }
    }
    float red[4] = {0.f, 0.f, 0.f, 0.f};
    #pragma unroll
    for (int t = 0; t < 8; ++t) {
      #pragma unroll
      for (int r = 0; r < 4; ++r)
        red[r] += t3w[t] * fmaxf(acc[t][r], 0.f);
    }
    #pragma unroll
    for (int r = 0; r < 4; ++r) {
      #pragma unroll
      for (int off = 1; off < 16; off <<= 1)
        red[r] += __shfl_xor(red[r], off, 64);
    }
    if (c == 0) {
      #pragma unroll
      for (int r = 0; r < 4; ++r) {
        int node = v0 + q*4 + r;
        if (node < n) out[node] = C + red[r];
      }
    }
  }
}

extern "C" void kernel_launch(void* const* d_in, const int* in_sizes, int n_in,
                              void* d_out, int out_size, void* d_ws, size_t ws_size,
                              hipStream_t stream)
{
  const float* sv  = (const float*)d_in[0];
  const float* tv  = (const float*)d_in[1];
  const float* x   = (const float*)d_in[2];
  const int*   esrc= (const int*)d_in[3];
  const int*   edst= (const int*)d_in[4];
  const float* th1 = (const float*)d_in[5];
  const float* th2 = (const float*)d_in[6];
  const float* th3 = (const float*)d_in[7];
  const float* th4 = (const float*)d_in[8];
  const float* th5 = (const float*)d_in[9];
  const float* hth = (const float*)d_in[10];
  float* out = (float*)d_out;
  const int n = in_sizes[0];
  const int e = in_sizes[3];

  const int nblk  = (e + CHUNK - 1) / CHUNK;     // 391 partition blocks
  const int nbuck = (n + 511) >> 9;              // 196 buckets
  const int NCS   = 120;                         // colsum partial blocks

  char* wp = (char*)d_ws;
  auto carve = [&](size_t bytes) { char* p = wp; wp += (bytes + 255) & ~(size_t)255; return p; };
  uint*   R1    = (uint*)  carve((size_t)n*128*2);  // packed -> mu' (aliased)
  ushort* mu_s  = (ushort*)carve((size_t)n*128*2);  // mu bf16 row-major
  ushort* rs_s  = (ushort*)carve((size_t)n*128*2);  // relu(s) bf16 row-major
  int*    sorted= (int*)   carve((size_t)e*4);
  int*    cnt   = (int*)   carve((size_t)n*4);
  int*    rowst = (int*)   carve((size_t)n*4);
  int*    histG = (int*)   carve((size_t)256*nblk*4);
  int*    btot  = (int*)   carve(256*4);
  int*    bbase = (int*)   carve(256*4);
  float*  part  = (float*) carve((size_t)NCS*128*4);
  float*  Cbuf  = (float*) carve(256);

  uint*   packed= (uint*)R1;     // dead before k_mlp writes mu'
  ushort* mup_s = (ushort*)R1;

  k_mu    <<<1024, 256, 0, stream>>>(x, sv, tv, th1, th2, mu_s, n);
  k_hist  <<<nblk, 256, 0, stream>>>(esrc, histG, e, nblk);
  k_scanH <<<256, 512, 0, stream>>>(histG, btot, nblk);
  k_scanB <<<1, 256, 0, stream>>>(btot, bbase);
  k_part  <<<nblk, 256, 0, stream>>>(esrc, edst, histG, bbase, packed, e, nblk);
  k_csr   <<<nbuck, 512, 0, stream>>>(packed, btot, bbase, sorted, rowst, cnt, n);
  k_gather<<<2048, 256, 0, stream>>>((const uint4*)mu_s, sorted, cnt, rowst,
                                     (uint4*)rs_s, n);
  k_mlp   <<<1024, 256, 0, stream>>>((const uint4*)mu_s, (const uint4*)rs_s,
                                     hth, mup_s, n);
  k_colsum<<<NCS, 256, 0, stream>>>((const uint*)mup_s, part, n);
  k_upC   <<<1, 128, 0, stream>>>(part, NCS, th4, th3, Cbuf);
  k_final <<<1024, 256, 0, stream>>>((const uint4*)mup_s, th5, th3, Cbuf, out, n);
}

// Round 10
// 454.140 us; speedup vs baseline: 2.6039x; 1.0680x over previous
//
#include <hip/hip_runtime.h>
#include <stdint.h>

typedef unsigned int uint;
typedef unsigned short ushort;
typedef __attribute__((ext_vector_type(4))) float f32x4;
typedef __attribute__((ext_vector_type(2))) float f32x2;
typedef __attribute__((ext_vector_type(8))) short bf16x8;   // 8 bf16 in 4 VGPRs

union U4H8 { uint4 u; bf16x8 h; };

__device__ __forceinline__ float bflo(uint u){ return __uint_as_float(u << 16); }
__device__ __forceinline__ float bfhi(uint u){ return __uint_as_float(u & 0xffff0000u); }
__device__ __forceinline__ ushort f2bf(float f){
  uint u = __float_as_uint(f);
  return (ushort)((u + 0x7fffu + ((u >> 16) & 1u)) >> 16);   // RNE
}
__device__ __forceinline__ uint pack2(float lo, float hi){
  return ((uint)f2bf(hi) << 16) | (uint)f2bf(lo);
}

// Software RNE encode f32 -> fp8 e4m3fn, f >= 0 (post-relu), saturate 448.
__device__ __forceinline__ uint fp8e(float f){
  uint u = __float_as_uint(f);
  uint r = u + 0x7FFFFu + ((u >> 20) & 1u);
  uint code = (((r >> 23) - 120u) << 3) | ((r >> 20) & 7u);
  code = (code > 0x7Eu) ? 0x7Eu : code;                  // saturate at 448
  uint den = (uint)__float2int_rn(f * 512.0f);           // 2^-9 denormal grid
  return (f >= 0.015625f) ? code : den;
}

// decode 4 fp8(e4m3) bytes of w into acc[off..off+3] (HW decode is exact)
__device__ __forceinline__ void fp8acc(float* acc, uint w, int off){
  f32x2 lo = __builtin_amdgcn_cvt_pk_f32_fp8(w, false);
  f32x2 hi = __builtin_amdgcn_cvt_pk_f32_fp8(w, true);
  acc[off+0] += lo[0]; acc[off+1] += lo[1];
  acc[off+2] += hi[0]; acc[off+3] += hi[1];
}

#define CHUNK 8192          // edges per partition block

// ---------------------------------------------------------------------------
// MFMA GEMM #1 (norm fused): mu[v][p] = relu((x/||x|| @ th2^T) + th1 conn)
// Emits mu twice: bf16 row-major (exact: GEMM A operand + gather self term)
// and fp8 e4m3 in a PERMUTED row layout (byte b = c*8 + t holds feature
// f = t*16 + c) used ONLY for the neighbor sum.
// D mapping: col=lane&15, row=(lane>>4)*4+reg  [m89/m91].
// ---------------------------------------------------------------------------
__global__ __launch_bounds__(256) void k_mu(
    const float* __restrict__ x, const float* __restrict__ sv,
    const float* __restrict__ tv, const float* __restrict__ th1,
    const float* __restrict__ th2, ushort* __restrict__ mu_s,
    uint2* __restrict__ mu8, int n)
{
  __shared__ uint4 B[2048];   // [s:4][t:8][lane:64], 32 KB
  const int tid = threadIdx.x;
  for (int f = tid; f < 2048; f += 256) {
    int l = f & 63, rest = f >> 6;          // rest: 0..31
    int s = rest >> 3, t = rest & 7;
    int row = t*16 + (l & 15);              // W row (output col p)
    int kb  = s*32 + (l >> 4)*8;
    const float* p = th2 + row*128 + kb;
    float4 a = *(const float4*)p;
    float4 b = *(const float4*)(p + 4);
    uint4 u; u.x = pack2(a.x,a.y); u.y = pack2(a.z,a.w);
    u.z = pack2(b.x,b.y); u.w = pack2(b.z,b.w);
    B[(s*8 + t)*64 + l] = u;
  }
  __syncthreads();
  const int w = tid >> 6, l = tid & 63, q = l >> 4, c = l & 15;
  float2 t1[8];
  #pragma unroll
  for (int t = 0; t < 8; ++t) t1[t] = ((const float2*)th1)[t*16 + c];
  const int ntiles = (n + 15) >> 4;
  for (int T = blockIdx.x*4 + w; T < ntiles; T += gridDim.x*4) {
    int v0 = T*16;
    int arow = min(v0 + c, n-1);
    const float4* xr = (const float4*)(x + (size_t)arow*128);
    float4 xf[8];
    #pragma unroll
    for (int s = 0; s < 4; ++s) {
      xf[2*s]   = xr[s*8 + q*2];
      xf[2*s+1] = xr[s*8 + q*2 + 1];
    }
    float ss = 0.f;
    #pragma unroll
    for (int i = 0; i < 8; ++i)
      ss += xf[i].x*xf[i].x + xf[i].y*xf[i].y + xf[i].z*xf[i].z + xf[i].w*xf[i].w;
    ss += __shfl_xor(ss, 16, 64);
    ss += __shfl_xor(ss, 32, 64);
    float inv = (ss > 0.f) ? rsqrtf(ss) : 1.f;
    U4H8 a[4];
    #pragma unroll
    for (int s = 0; s < 4; ++s) {
      float4 u0 = xf[2*s], u1 = xf[2*s+1];
      a[s].u = make_uint4(pack2(u0.x*inv, u0.y*inv), pack2(u0.z*inv, u0.w*inv),
                          pack2(u1.x*inv, u1.y*inv), pack2(u1.z*inv, u1.w*inv));
    }
    f32x4 acc[8];
    #pragma unroll
    for (int t = 0; t < 8; ++t) acc[t] = (f32x4){0.f,0.f,0.f,0.f};
    #pragma unroll
    for (int s = 0; s < 4; ++s) {
      #pragma unroll
      for (int t = 0; t < 8; ++t) {
        U4H8 b; b.u = B[(s*8 + t)*64 + l];
        acc[t] = __builtin_amdgcn_mfma_f32_16x16x32_bf16(a[s].h, b.h, acc[t], 0, 0, 0);
      }
    }
    float svr[4], tvr[4];
    #pragma unroll
    for (int r = 0; r < 4; ++r) {
      int node = min(v0 + q*4 + r, n-1);
      svr[r] = sv[node]; tvr[r] = tv[node];
    }
    #pragma unroll
    for (int r = 0; r < 4; ++r) {
      int node = v0 + q*4 + r;
      if (node < n) {
        float mm[8];
        #pragma unroll
        for (int t = 0; t < 8; ++t) {
          mm[t] = fmaxf(acc[t][r] + t1[t].x*svr[r] + t1[t].y*tvr[r], 0.f);
          mu_s[(size_t)node*128 + t*16 + c] = f2bf(mm[t]);
        }
        uint u0 = fp8e(mm[0]) | (fp8e(mm[1]) << 8) |
                  (fp8e(mm[2]) << 16) | (fp8e(mm[3]) << 24);
        uint u1 = fp8e(mm[4]) | (fp8e(mm[5]) << 8) |
                  (fp8e(mm[6]) << 16) | (fp8e(mm[7]) << 24);
        mu8[(size_t)node*16 + c] = make_uint2(u0, u1);   // bytes c*8..c*8+7
      }
    }
  }
}

// ---------------------------------------------------------------------------
// M2 = th5 @ h_theta  (128x256, tiny). Block r computes row r.
// ---------------------------------------------------------------------------
__global__ __launch_bounds__(256) void k_m2(const float* __restrict__ th5,
    const float* __restrict__ hth, float* __restrict__ M2)
{
  __shared__ float row[128];
  const int r = blockIdx.x, j = threadIdx.x;
  if (j < 128) row[j] = th5[r*128 + j];
  __syncthreads();
  float acc = 0.f;
  #pragma unroll 8
  for (int k = 0; k < 128; ++k) acc += row[k] * hth[k*256 + j];
  M2[r*256 + j] = acc;
}

// --------------------- CSR build: 2-phase bucket partition ------------------
// bucket = src>>9. Per-block ranking via LDS histogram + scan; no global
// atomic cursors (round-3: contended device atomics ~183 ns/op/address).

__global__ __launch_bounds__(256) void k_hist(const int* __restrict__ src,
    int* __restrict__ histG, int e, int nblk)
{
  __shared__ int lh[256];
  const int blk = blockIdx.x, tid = threadIdx.x;
  lh[tid] = 0; __syncthreads();
  const int lo = blk*CHUNK, hi = min(e, lo + CHUNK);
  for (int i = lo + tid; i < hi; i += 256)
    atomicAdd(&lh[src[i] >> 9], 1);
  __syncthreads();
  histG[tid*nblk + blk] = lh[tid];   // layout [bucket][block]
}

__global__ __launch_bounds__(512) void k_scanH(int* __restrict__ histG,
    int* __restrict__ bucketTot, int nblk)
{
  __shared__ int tmp[512];
  const int b = blockIdx.x, tid = threadIdx.x;
  int v = (tid < nblk) ? histG[b*nblk + tid] : 0;
  tmp[tid] = v; __syncthreads();
  for (int off = 1; off < 512; off <<= 1) {
    int t = (tid >= off) ? tmp[tid - off] : 0;
    __syncthreads();
    tmp[tid] += t;
    __syncthreads();
  }
  if (tid < nblk) histG[b*nblk + tid] = tmp[tid] - v;   // exclusive
  if (tid == nblk - 1) bucketTot[b] = tmp[tid];
}

__global__ __launch_bounds__(256) void k_scanB(const int* __restrict__ bucketTot,
    int* __restrict__ bucketBase)
{
  __shared__ int tmp[256];
  int tid = threadIdx.x;
  int v = bucketTot[tid];
  tmp[tid] = v; __syncthreads();
  for (int off = 1; off < 256; off <<= 1) {
    int t = (tid >= off) ? tmp[tid - off] : 0;
    __syncthreads();
    tmp[tid] += t;
    __syncthreads();
  }
  bucketBase[tid] = tmp[tid] - v;
}

__global__ __launch_bounds__(256) void k_part(
    const int* __restrict__ src, const int* __restrict__ dst,
    const int* __restrict__ histG, const int* __restrict__ bucketBase,
    uint* __restrict__ packed, int e, int nblk)
{
  __shared__ int cur[256];
  const int blk = blockIdx.x, tid = threadIdx.x;
  cur[tid] = bucketBase[tid] + histG[tid*nblk + blk];
  __syncthreads();
  const int lo = blk*CHUNK, hi = min(e, lo + CHUNK);
  for (int i = lo + tid; i < hi; i += 256) {
    int s = src[i], d = dst[i];
    int pos = atomicAdd(&cur[s >> 9], 1);
    packed[pos] = ((uint)(s & 511) << 17) | (uint)d;
  }
}

__global__ __launch_bounds__(512) void k_csr(
    const uint* __restrict__ packed, const int* __restrict__ bucketTot,
    const int* __restrict__ bucketBase, int* __restrict__ sorted,
    int* __restrict__ rowstart, int* __restrict__ cnt, int n)
{
  __shared__ int lc[512];
  __shared__ int lofs[512];
  __shared__ int lcur[512];
  const int b = blockIdx.x, tid = threadIdx.x;
  const int base = bucketBase[b], tot = bucketTot[b];
  lc[tid] = 0; __syncthreads();
  for (int i = tid; i < tot; i += 512)
    atomicAdd(&lc[packed[base + i] >> 17], 1);
  __syncthreads();
  lofs[tid] = lc[tid]; __syncthreads();
  for (int off = 1; off < 512; off <<= 1) {
    int t = (tid >= off) ? lofs[tid - off] : 0;
    __syncthreads();
    lofs[tid] += t;
    __syncthreads();
  }
  int excl = lofs[tid] - lc[tid];
  int node = (b << 9) + tid;
  lcur[tid] = base + excl;
  if (node < n) { rowstart[node] = base + excl; cnt[node] = lc[tid]; }
  __syncthreads();
  for (int i = tid; i < tot; i += 512) {
    uint p = packed[base + i];
    int pos = atomicAdd(&lcur[p >> 17], 1);
    sorted[pos] = (int)(p & 0x1FFFFu);
  }
}

// ---------------------------------------------------------------------------
// Gather: rs[v] = relu(deg*mu[v] - sum_{u in N(v)} mu[u])
// Neighbor sum from RNE fp8 rows (128 B, 8 edges/wave-load); self term from
// exact bf16 mu. acc[k] = permuted feature f = (k&7)*16 + 2c + (k>>3).
// ROUND-9 BUG FIX: the remainder __shfl MUST be wave-uniform. In rounds 7-9
// it sat inside `if (g < rem)`; the source lane full+g is usually inactive
// there, and ds_bpermute from an inactive lane is UNDEFINED -> deterministic
// garbage neighbor rows -> the invariant absmax 11776 across all numeric
// changes. All lanes now execute the shfl (min(g,rem-1) source, like the
// passing round-6 kernel); only the accumulate is predicated.
// ---------------------------------------------------------------------------
__global__ __launch_bounds__(256) void k_gather(
    const uint4* __restrict__ mu8, const uint* __restrict__ mu_u,
    const int* __restrict__ sorted, const int* __restrict__ cnt,
    const int* __restrict__ rowstart, uint* __restrict__ rs_u, int n)
{
  const int w = threadIdx.x >> 6, l = threadIdx.x & 63;
  const int g = l >> 3, c = l & 7;
  for (int v = blockIdx.x*4 + w; v < n; v += gridDim.x*4) {
    int deg = cnt[v], start = rowstart[v];
    float acc[16];
    #pragma unroll
    for (int i = 0; i < 16; ++i) acc[i] = 0.f;
    for (int base = 0; base < deg; base += 64) {
      int m = min(deg - base, 64);
      int idx = (l < m) ? sorted[start + base + l] : 0;
      int full = m & ~7;
      for (int j = 0; j < full; j += 8) {
        int d = __shfl(idx, j + g, 64);            // uniform trip count: safe
        uint4 u = mu8[(size_t)d*8 + c];
        fp8acc(acc, u.x, 0); fp8acc(acc, u.y, 4);
        fp8acc(acc, u.z, 8); fp8acc(acc, u.w, 12);
      }
      int rem = m - full;
      if (rem) {                                   // WAVE-UNIFORM branch
        int d = __shfl(idx, full + min(g, rem-1), 64);  // all 64 lanes execute
        if (g < rem) {                             // predicate load+accumulate
          uint4 u = mu8[(size_t)d*8 + c];
          fp8acc(acc, u.x, 0); fp8acc(acc, u.y, 4);
          fp8acc(acc, u.z, 8); fp8acc(acc, u.w, 12);
        }
      }
    }
    #pragma unroll
    for (int i = 0; i < 16; ++i) {
      acc[i] += __shfl_xor(acc[i], 8, 64);
      acc[i] += __shfl_xor(acc[i], 16, 64);
      acc[i] += __shfl_xor(acc[i], 32, 64);
    }
    if (g == 0) {
      float dg = (float)deg;
      #pragma unroll
      for (int mi = 0; mi < 8; ++mi) {
        uint um = mu_u[(size_t)v*64 + mi*8 + c];   // exact bf16: features 16mi+2c, +1
        float s0 = fmaxf(dg*bflo(um) - acc[mi],   0.f);
        float s1 = fmaxf(dg*bfhi(um) - acc[mi+8], 0.f);
        rs_u[(size_t)v*64 + mi*8 + c] = pack2(s0, s1);
      }
    }
  }
}

// column partial sums of q = [mu ; rs] -> part[blockIdx][256]  (no atomics)
__global__ __launch_bounds__(256) void k_colsum(const uint* __restrict__ mu_u,
    const uint* __restrict__ rs_u, float* __restrict__ part, int n) {
  __shared__ float ls[4*256];
  int w = threadIdx.x >> 6, l = threadIdx.x & 63;
  float a0 = 0.f, a1 = 0.f, b0 = 0.f, b1 = 0.f;
  for (int v = blockIdx.x*4 + w; v < n; v += gridDim.x*4) {
    uint u = mu_u[(size_t)v*64 + l];
    a0 += bflo(u); a1 += bfhi(u);
    uint r = rs_u[(size_t)v*64 + l];
    b0 += bflo(r); b1 += bfhi(r);
  }
  ls[w*256 + 2*l]       = a0;
  ls[w*256 + 2*l+1]     = a1;
  ls[w*256 + 128 + 2*l]   = b0;
  ls[w*256 + 128 + 2*l+1] = b1;
  __syncthreads();
  int tid = threadIdx.x;
  part[(size_t)blockIdx.x*256 + tid] =
      ls[tid] + ls[256+tid] + ls[512+tid] + ls[768+tid];
}

// reduce partials -> q256; gsum = hth@q256; up = th4@gsum; C -> Cbuf
__global__ __launch_bounds__(128) void k_upC(const float* __restrict__ part,
    int npart, const float* __restrict__ hth, const float* __restrict__ th4,
    const float* __restrict__ th3, float* __restrict__ Cbuf) {
  __shared__ float Q[256];
  __shared__ float S[128];
  __shared__ float pr[128];
  int tid = threadIdx.x;
  float q0 = 0.f, q1 = 0.f;
  for (int b = 0; b < npart; ++b) {
    q0 += part[(size_t)b*256 + tid];
    q1 += part[(size_t)b*256 + 128 + tid];
  }
  Q[tid] = q0; Q[128 + tid] = q1;
  __syncthreads();
  float gs = 0.f;
  const float4* hr = (const float4*)(hth + tid*256);
  const float4* Q4 = (const float4*)Q;
  #pragma unroll 8
  for (int k = 0; k < 64; ++k) {
    float4 a = hr[k], b = Q4[k];
    gs += a.x*b.x + a.y*b.y + a.z*b.z + a.w*b.w;
  }
  S[tid] = gs;
  __syncthreads();
  float up = 0.f;
  const float4* r4 = (const float4*)(th4 + tid*128);
  const float4* S4 = (const float4*)S;
  #pragma unroll 8
  for (int k = 0; k < 32; ++k) {
    float4 a = r4[k], b = S4[k];
    up += a.x*b.x + a.y*b.y + a.z*b.z + a.w*b.w;
  }
  float r = th3[tid] * fmaxf(up, 0.f);
  pr[tid] = r; __syncthreads();
  if (tid < 64) pr[tid] += pr[tid + 64];
  __syncthreads();
  if (tid < 64) {
    float v = pr[tid];
    #pragma unroll
    for (int off = 32; off > 0; off >>= 1) v += __shfl_down(v, off, 64);
    if (tid == 0) Cbuf[0] = v;
  }
}

// ---------------------------------------------------------------------------
// MFMA GEMM #2 (merged mlp+final): down_v = M2 @ [mu;rs]_v  (K=256),
// out[v] = C + sum_p th3[128+p]*relu(down_v[p]).  mu' never materialized.
// ---------------------------------------------------------------------------
__global__ __launch_bounds__(256) void k_out(
    const uint4* __restrict__ mu4, const uint4* __restrict__ rs4,
    const float* __restrict__ M2, const float* __restrict__ th3,
    const float* __restrict__ Cbuf, float* __restrict__ out, int n)
{
  __shared__ uint4 B[4096];   // [s:8][t:8][lane:64], 64 KB
  const int tid = threadIdx.x;
  for (int f = tid; f < 4096; f += 256) {
    int l = f & 63, rest = f >> 6;          // 0..63
    int s = rest >> 3, t = rest & 7;
    int row = t*16 + (l & 15);
    int kb  = s*32 + (l >> 4)*8;
    const float* p = M2 + row*256 + kb;
    float4 a = *(const float4*)p;
    float4 b = *(const float4*)(p + 4);
    uint4 u; u.x = pack2(a.x,a.y); u.y = pack2(a.z,a.w);
    u.z = pack2(b.x,b.y); u.w = pack2(b.z,b.w);
    B[(s*8 + t)*64 + l] = u;
  }
  __syncthreads();
  const int w = tid >> 6, l = tid & 63, q = l >> 4, c = l & 15;
  float t3w[8];
  #pragma unroll
  for (int t = 0; t < 8; ++t) t3w[t] = th3[128 + t*16 + c];
  const float C = Cbuf[0];
  const int ntiles = (n + 15) >> 4;
  for (int T = blockIdx.x*4 + w; T < ntiles; T += gridDim.x*4) {
    int v0 = T*16;
    int arow = min(v0 + c, n-1);
    U4H8 a[8];
    #pragma unroll
    for (int s = 0; s < 4; ++s) a[s].u   = mu4[(size_t)arow*16 + s*4 + q];
    #pragma unroll
    for (int s = 0; s < 4; ++s) a[4+s].u = rs4[(size_t)arow*16 + s*4 + q];
    f32x4 acc[8];
    #pragma unroll
    for (int t = 0; t < 8; ++t) acc[t] = (f32x4){0.f,0.f,0.f,0.f};
    #pragma unroll
    for (int s = 0; s < 8; ++s) {
      #pragma unroll
      for (int t = 0; t < 8; ++t) {
        U4H8 b; b.u = B[(s*8 + t)*64 + l];
        acc[t] = __builtin_amdgcn_mfma_f32_16x16x32_bf16(a[s].h, b.h, acc[t], 0, 0, 0);
      }
    }
    float red[4] = {0.f, 0.f, 0.f, 0.f};
    #pragma unroll
    for (int t = 0; t < 8; ++t) {
      #pragma unroll
      for (int r = 0; r < 4; ++r)
        red[r] += t3w[t] * fmaxf(acc[t][r], 0.f);
    }
    #pragma unroll
    for (int r = 0; r < 4; ++r) {
      #pragma unroll
      for (int off = 1; off < 16; off <<= 1)
        red[r] += __shfl_xor(red[r], off, 64);
    }
    if (c == 0) {
      #pragma unroll
      for (int r = 0; r < 4; ++r) {
        int node = v0 + q*4 + r;
        if (node < n) out[node] = C + red[r];
      }
    }
  }
}

extern "C" void kernel_launch(void* const* d_in, const int* in_sizes, int n_in,
                              void* d_out, int out_size, void* d_ws, size_t ws_size,
                              hipStream_t stream)
{
  const float* sv  = (const float*)d_in[0];
  const float* tv  = (const float*)d_in[1];
  const float* x   = (const float*)d_in[2];
  const int*   esrc= (const int*)d_in[3];
  const int*   edst= (const int*)d_in[4];
  const float* th1 = (const float*)d_in[5];
  const float* th2 = (const float*)d_in[6];
  const float* th3 = (const float*)d_in[7];
  const float* th4 = (const float*)d_in[8];
  const float* th5 = (const float*)d_in[9];
  const float* hth = (const float*)d_in[10];
  float* out = (float*)d_out;
  const int n = in_sizes[0];
  const int e = in_sizes[3];

  const int nblk  = (e + CHUNK - 1) / CHUNK;     // 391 partition blocks
  const int nbuck = (n + 511) >> 9;              // 196 buckets
  const int NCS   = 120;                         // colsum partial blocks

  char* wp = (char*)d_ws;
  auto carve = [&](size_t bytes) { char* p = wp; wp += (bytes + 255) & ~(size_t)255; return p; };
  // R1 (25.6 MB): [0, e*4) = packed (k_part..k_csr);
  //               [n*128, 2*n*128) = mu8 fp8 (k_mu..k_gather)   [disjoint]
  char*   R1    = (char*) carve((size_t)n*128*2);
  ushort* mu_s  = (ushort*)carve((size_t)n*128*2);  // mu bf16 row-major (exact)
  ushort* rs_s  = (ushort*)carve((size_t)n*128*2);  // relu(s) bf16 row-major
  int*    sorted= (int*)   carve((size_t)e*4);
  int*    cnt   = (int*)   carve((size_t)n*4);
  int*    rowst = (int*)   carve((size_t)n*4);
  int*    histG = (int*)   carve((size_t)256*nblk*4);
  int*    btot  = (int*)   carve(256*4);
  int*    bbase = (int*)   carve(256*4);
  float*  M2    = (float*) carve(128*256*4);
  float*  part  = (float*) carve((size_t)NCS*256*4);
  float*  Cbuf  = (float*) carve(256);

  uint*   packed= (uint*)R1;                     // lower 12.8 MB
  uint2*  mu8   = (uint2*)(R1 + (size_t)n*128);  // upper 12.8 MB

  k_mu    <<<1024, 256, 0, stream>>>(x, sv, tv, th1, th2, mu_s, mu8, n);
  k_m2    <<<128, 256, 0, stream>>>(th5, hth, M2);
  k_hist  <<<nblk, 256, 0, stream>>>(esrc, histG, e, nblk);
  k_scanH <<<256, 512, 0, stream>>>(histG, btot, nblk);
  k_scanB <<<1, 256, 0, stream>>>(btot, bbase);
  k_part  <<<nblk, 256, 0, stream>>>(esrc, edst, histG, bbase, packed, e, nblk);
  k_csr   <<<nbuck, 512, 0, stream>>>(packed, btot, bbase, sorted, rowst, cnt, n);
  k_gather<<<2048, 256, 0, stream>>>((const uint4*)mu8, (const uint*)mu_s,
                                     sorted, cnt, rowst, (uint*)rs_s, n);
  k_colsum<<<NCS, 256, 0, stream>>>((const uint*)mu_s, (const uint*)rs_s, part, n);
  k_upC   <<<1, 128, 0, stream>>>(part, NCS, hth, th4, th3, Cbuf);
  k_out   <<<1024, 256, 0, stream>>>((const uint4*)mu_s, (const uint4*)rs_s,
                                     M2, th3, Cbuf, out, n);
}